// Round 6
// baseline (484.946 us; speedup 1.0000x reference)
//
#include <hip/hip_runtime.h>
#include <hip/hip_fp16.h>
#include <math.h>

#define BIG_NEG  (-1.0e6f)
#define NN   100
#define MD   128
#define KD   256
#define G4   512
#define MP2  68   // __half2 stride per mem row: 272 B = 17*16 (16B-aligned, <=2-way banks)

// ws layout:
//   halves [0, 32768)       : WembF embed B-frags [kg:32][m:128][j:8]
//   halves [32768, 163840)  : WGF gates B-frags [kc:32][g:512][j:8], k = kc*8+j
//   floats [81920, 82432)   : biasc = b_ih + b_hh
#define WS_WGF_H  32768
#define WS_BIAS_F 81920

typedef _Float16 f16x2 __attribute__((ext_vector_type(2)));
typedef _Float16 f16x8 __attribute__((ext_vector_type(8)));
typedef float    f32x4 __attribute__((ext_vector_type(4)));

__device__ __forceinline__ float sigm(float x) { return 1.0f / (1.0f + __expf(-x)); }

extern "C" __global__ void prep_kernel(const float* __restrict__ W_emb,
                                       const float* __restrict__ W_ih,
                                       const float* __restrict__ b_ih,
                                       const float* __restrict__ W_hh,
                                       const float* __restrict__ b_hh,
                                       float* __restrict__ ws) {
    int tid = blockIdx.x * blockDim.x + threadIdx.x;
    int nth = gridDim.x * blockDim.x;
    __half* WF    = (__half*)ws;
    __half* WG    = (__half*)ws + WS_WGF_H;
    float*  biasc = ws + WS_BIAS_F;
    // embed B-frag: lane needs W_emb[k = kg*8+j][m]
    for (int i = tid; i < 32768; i += nth) {
        int kg = i >> 10, m = (i >> 3) & 127, j = i & 7;
        WF[i] = __float2half(W_emb[m * 256 + kg * 8 + j]);
    }
    // gates B-frag: WG[((kc*512)+g)*8+j] = Wcat[k = kc*8+j][g]
    for (int i = tid; i < 131072; i += nth) {
        int kc = i >> 12, g = (i >> 3) & 511, j = i & 7;
        int k = kc * 8 + j;
        float w = (k < 128) ? W_ih[g * 128 + k] : W_hh[g * 128 + (k - 128)];
        WG[i] = __float2half(w);
    }
    for (int i = tid; i < 512; i += nth) biasc[i] = b_ih[i] + b_hh[i];
}

extern "C" __global__ __launch_bounds__(1024, 8)
void set2vec_main(const float* __restrict__ hidden,
                  const float* __restrict__ input,
                  const float* __restrict__ b_emb,
                  const unsigned char* __restrict__ mask_bytes,
                  const int* __restrict__ Tptr,
                  const float* __restrict__ ws,
                  float* __restrict__ out) {
    __shared__ __half2 mem2[2][NN][MP2];     // 54400 B fp16 memory [bb][n][m-pair]
    __shared__ __half  xcath[2][KD];         // fp16 [lstm_in | h] (gates A operand)
    __shared__ float   xcat2[2][KD];         // fp32 [lstm_in | h] (energies/output)
    __shared__ float   cbuf[2][MD];
    __shared__ float   emask[2][NN];
    __shared__ float   bbuf[G4];             // bias staged in LDS
    __shared__ int     mask_is_u8;
    __shared__ float   gbuf[2][G4];          // gates output [bb][g]
    __shared__ float   epart[2][4][NN];      // [bb][mq][n]
    __shared__ float   abuf[2][NN];

    const int tid  = threadIdx.x;
    const int b0   = blockIdx.x * 2;
    const int lane = tid & 63, wv = tid >> 6;
    const int ln15 = lane & 15, lhi = lane >> 4;
    const __half* WF = (const __half*)ws;

    if (tid == 0) {
        int nz = 0;
        for (int i = 0; i < 64; ++i)
            if ((i & 3) && mask_bytes[i]) nz = 1;
        mask_is_u8 = nz;
    }

    // ---- fused embed via MFMA: mem = fp16(cat(hidden,input) @ W_emb^T + b_emb) ----
    {
        if (wv < 13) {
            float be0 = b_emb[0 * 16 + ln15], be1 = b_emb[1 * 16 + ln15];
            float be2 = b_emb[2 * 16 + ln15], be3 = b_emb[3 * 16 + ln15];
            float be4 = b_emb[4 * 16 + ln15], be5 = b_emb[5 * 16 + ln15];
            float be6 = b_emb[6 * 16 + ln15], be7 = b_emb[7 * 16 + ln15];
            f32x4 acc0 = {be0, be0, be0, be0}, acc1 = {be1, be1, be1, be1};
            f32x4 acc2 = {be2, be2, be2, be2}, acc3 = {be3, be3, be3, be3};
            f32x4 acc4 = {be4, be4, be4, be4}, acc5 = {be5, be5, be5, be5};
            f32x4 acc6 = {be6, be6, be6, be6}, acc7 = {be7, be7, be7, be7};

            const int rA     = wv * 16 + ln15;
            const int rAok   = rA < 200;
            const long gbase = ((long)(b0 * 100 + rA)) << 7;

            for (int mk = 0; mk < 8; ++mk) {
                f16x8 aF;
                if (rAok) {
                    int k0 = mk * 32 + lhi * 8;
                    const float* src = (k0 < 128) ? (hidden + gbase + k0)
                                                  : (input + gbase + (k0 - 128));
                    float4 v0 = *(const float4*)src;
                    float4 v1 = *(const float4*)(src + 4);
                    union { f16x8 v; f16x2 h[4]; } au;
                    au.h[0] = __builtin_bit_cast(f16x2, __builtin_amdgcn_cvt_pkrtz(v0.x, v0.y));
                    au.h[1] = __builtin_bit_cast(f16x2, __builtin_amdgcn_cvt_pkrtz(v0.z, v0.w));
                    au.h[2] = __builtin_bit_cast(f16x2, __builtin_amdgcn_cvt_pkrtz(v1.x, v1.y));
                    au.h[3] = __builtin_bit_cast(f16x2, __builtin_amdgcn_cvt_pkrtz(v1.z, v1.w));
                    aF = au.v;
                } else {
                    aF = (f16x8)(_Float16)0.0f;
                }
                const __half* wrow = WF + ((mk * 4 + lhi) * 128 + ln15) * 8;
#define EMB_CT(CT, ACC) { \
                union { uint4 u; f16x8 v; } bu; \
                bu.u = *(const uint4*)(wrow + (CT * 16) * 8); \
                ACC = __builtin_amdgcn_mfma_f32_16x16x32_f16(aF, bu.v, ACC, 0, 0, 0); }
                EMB_CT(0, acc0) EMB_CT(1, acc1) EMB_CT(2, acc2) EMB_CT(3, acc3)
                EMB_CT(4, acc4) EMB_CT(5, acc5) EMB_CT(6, acc6) EMB_CT(7, acc7)
#undef EMB_CT
            }
            __half* memh = (__half*)mem2;
#define EMB_WR(CT, ACC) { \
            _Pragma("unroll") \
            for (int reg = 0; reg < 4; ++reg) { \
                int r = wv * 16 + lhi * 4 + reg; \
                if (r < 200) { \
                    int bb = r >= 100, n = r - (r >= 100) * 100; \
                    memh[(bb * 100 + n) * (2 * MP2) + CT * 16 + ln15] = __float2half(ACC[reg]); \
                } } }
            EMB_WR(0, acc0) EMB_WR(1, acc1) EMB_WR(2, acc2) EMB_WR(3, acc3)
            EMB_WR(4, acc4) EMB_WR(5, acc5) EMB_WR(6, acc6) EMB_WR(7, acc7)
#undef EMB_WR
        }
    }

    // ---- init LSTM state + mask + bias tables ----
    for (int i = tid; i < 2 * KD; i += 1024) ((float*)xcat2)[i] = 0.0f;
    if (tid < 512) {
        ((__half*)xcath)[tid] = __float2half(0.0f);
        bbuf[tid] = ws[WS_BIAS_F + tid];
    }
    if (tid < 256) ((float*)cbuf)[tid] = 0.0f;
    if (tid < 2 * NN) {
        int bb = tid >= NN, n = tid - bb * NN;
        long mrow = (long)(b0 + bb) * NN + n;
        int valid = mask_is_u8 ? (mask_bytes[mrow] != 0)
                               : (((const int*)mask_bytes)[mrow] != 0);
        emask[bb][n] = valid ? 0.0f : BIG_NEG;
    }
    __syncthreads();

    const int T = Tptr[0];

    // ---- per-thread phase constants ----
    const uint4* WgB = (const uint4*)((const __half*)ws + WS_WGF_H);
    const int ct0 = wv * 2, ct1 = wv * 2 + 1;
    const __half* aBase = &xcath[ln15 & 1][lhi * 8];   // batch-duplicated A rows

    const int e_act = tid < 800;
    const int e_bb  = tid / 400;
    const int e_r   = tid - e_bb * 400;
    const int e_mq  = e_r / 100;
    const int e_n   = e_r - e_mq * 100;

    for (int step = 0; step < T; ++step) {
        // --- gates via MFMA: X[2,256] @ Wcat^T -> gbuf[2][512] ---
        {
            f32x4 ga = {0.f, 0.f, 0.f, 0.f}, gb = {0.f, 0.f, 0.f, 0.f};
            #pragma unroll
            for (int ks = 0; ks < 8; ++ks) {
                union { uint4 u; f16x8 v; } a, bA, bB;
                a.u = *(const uint4*)(aBase + ks * 32);
                int kc = ks * 4 + lhi;
                bA.u = WgB[kc * 512 + ct0 * 16 + ln15];
                bB.u = WgB[kc * 512 + ct1 * 16 + ln15];
                ga = __builtin_amdgcn_mfma_f32_16x16x32_f16(a.v, bA.v, ga, 0, 0, 0);
                gb = __builtin_amdgcn_mfma_f32_16x16x32_f16(a.v, bB.v, gb, 0, 0, 0);
            }
            if (lhi == 0) {   // D rows 0,1 = batch 0,1
                gbuf[0][ct0 * 16 + ln15] = ga[0];
                gbuf[1][ct0 * 16 + ln15] = ga[1];
                gbuf[0][ct1 * 16 + ln15] = gb[0];
                gbuf[1][ct1 * 16 + ln15] = gb[1];
            }
        }
        __syncthreads();
        // --- LSTM pointwise (i,f,g,o) ---
        if (tid < 256) {
            int bb = tid >> 7, m = tid & 127;
            float gi = gbuf[bb][m]       + bbuf[m];
            float gf = gbuf[bb][128 + m] + bbuf[128 + m];
            float gg = gbuf[bb][256 + m] + bbuf[256 + m];
            float go = gbuf[bb][384 + m] + bbuf[384 + m];
            float c  = cbuf[bb][m];
            c = sigm(gf) * c + sigm(gi) * tanhf(gg);
            float qv = sigm(go) * tanhf(c);
            cbuf[bb][m] = c;
            xcat2[bb][128 + m] = qv;
            xcath[bb][128 + m] = __float2half(qv);
        }
        __syncthreads();
        // --- energies partial: M in quarters, vectorized LDS ---
        if (e_act) {
            const uint4*  mr4 = (const uint4*)&mem2[e_bb][e_n][e_mq * 16];
            const float4* qv4 = (const float4*)&xcat2[e_bb][128 + e_mq * 32];
            float e = 0.0f;
            #pragma unroll
            for (int i = 0; i < 4; ++i) {
                uint4  mu = mr4[i];
                float4 qa = qv4[2 * i], qb = qv4[2 * i + 1];
                float2 m0 = __half22float2(*(__half2*)&mu.x);
                float2 m1 = __half22float2(*(__half2*)&mu.y);
                float2 m2 = __half22float2(*(__half2*)&mu.z);
                float2 m3 = __half22float2(*(__half2*)&mu.w);
                e = fmaf(qa.x, m0.x, e); e = fmaf(qa.y, m0.y, e);
                e = fmaf(qa.z, m1.x, e); e = fmaf(qa.w, m1.y, e);
                e = fmaf(qb.x, m2.x, e); e = fmaf(qb.y, m2.y, e);
                e = fmaf(qb.z, m3.x, e); e = fmaf(qb.w, m3.y, e);
            }
            epart[0][0][tid] = e;   // flat [bb][mq][n]
        }
        __syncthreads();
        // --- softmax ---
        if (tid < 128) {
            int bb = tid >> 6, l = tid & 63;
            const float* ep = &epart[bb][0][0];
            float e0 = ep[l] + ep[100 + l] + ep[200 + l] + ep[300 + l] + emask[bb][l];
            float e1 = -INFINITY;
            if (l < 36) {
                int n1 = l + 64;
                e1 = ep[n1] + ep[100 + n1] + ep[200 + n1] + ep[300 + n1] + emask[bb][n1];
            }
            float mx = fmaxf(e0, e1);
            for (int off = 32; off; off >>= 1) mx = fmaxf(mx, __shfl_xor(mx, off, 64));
            float p0 = __expf(e0 - mx);
            float p1 = (l < 36) ? __expf(e1 - mx) : 0.0f;
            float s = p0 + p1;
            for (int off = 32; off; off >>= 1) s += __shfl_xor(s, off, 64);
            float inv = 1.0f / s;
            abuf[bb][l] = p0 * inv;
            if (l < 36) abuf[bb][l + 64] = p1 * inv;
        }
        __syncthreads();
        // --- read: thread = (bb, m-pair), both halves of each __half2 used ---
        if (tid < 128) {
            int bb = tid >> 6, mp = tid & 63;
            const float*   ar  = abuf[bb];
            const __half2* mrp = &mem2[bb][0][mp];
            float r0 = 0, r1 = 0, r2 = 0, r3 = 0, s0 = 0, s1 = 0, s2 = 0, s3 = 0;
            #pragma unroll 5
            for (int n = 0; n < 100; n += 4) {
                float4  av = *(const float4*)(ar + n);
                __half2 h0 = mrp[n * MP2],       h1 = mrp[(n + 1) * MP2];
                __half2 h2 = mrp[(n + 2) * MP2], h3 = mrp[(n + 3) * MP2];
                float2 f0 = __half22float2(h0), f1 = __half22float2(h1);
                float2 f2 = __half22float2(h2), f3 = __half22float2(h3);
                r0 = fmaf(av.x, f0.x, r0); s0 = fmaf(av.x, f0.y, s0);
                r1 = fmaf(av.y, f1.x, r1); s1 = fmaf(av.y, f1.y, s1);
                r2 = fmaf(av.z, f2.x, r2); s2 = fmaf(av.z, f2.y, s2);
                r3 = fmaf(av.w, f3.x, r3); s3 = fmaf(av.w, f3.y, s3);
            }
            float rx = (r0 + r1) + (r2 + r3);
            float ry = (s0 + s1) + (s2 + s3);
            int m = mp * 2;
            xcat2[bb][m]     = rx;
            xcat2[bb][m + 1] = ry;
            xcath[bb][m]     = __float2half(rx);
            xcath[bb][m + 1] = __float2half(ry);
        }
        __syncthreads();
    }

    // ---- output: [q | read] ----
    if (tid < 512) {
        int bb = tid >> 8, j = tid & 255;
        float v = (j < 128) ? xcat2[bb][128 + j] : xcat2[bb][j - 128];
        out[((long)(b0 + bb) << 8) + j] = v;
    }
}

extern "C" void kernel_launch(void* const* d_in, const int* in_sizes, int n_in,
                              void* d_out, int out_size, void* d_ws, size_t ws_size,
                              hipStream_t stream) {
    const float* hidden = (const float*)d_in[0];
    const float* input  = (const float*)d_in[1];
    const float* W_emb  = (const float*)d_in[2];
    const float* b_emb  = (const float*)d_in[3];
    const float* W_ih   = (const float*)d_in[4];
    const float* b_ih   = (const float*)d_in[5];
    const float* W_hh   = (const float*)d_in[6];
    const float* b_hh   = (const float*)d_in[7];
    const unsigned char* mask = (const unsigned char*)d_in[8];
    const int*  Tptr    = (const int*)d_in[9];
    float* ws   = (float*)d_ws;
    float* outp = (float*)d_out;

    hipLaunchKernelGGL(prep_kernel, dim3(128), dim3(256), 0, stream,
                       W_emb, W_ih, b_ih, W_hh, b_hh, ws);
    hipLaunchKernelGGL(set2vec_main, dim3(1024), dim3(1024), 0, stream,
                       hidden, input, b_emb, mask, Tptr, ws, outp);
}

// Round 7
// 201.079 us; speedup vs baseline: 2.4117x; 2.4117x over previous
//
#include <hip/hip_runtime.h>
#include <hip/hip_fp16.h>
#include <math.h>

#define BIG_NEG  (-1.0e6f)
#define NN   100
#define MD   128
#define KD   256
#define G4   512
#define NB   4    // batch elements per block
#define MP2  68   // __half2 stride per mem row (272 B, 16B-aligned)

// ws layout:
//   halves [0, 32768)       : WembF embed B-frags [kg:32][m:128][j:8]
//   halves [32768, 163840)  : WGF gates B-frags [kc:32][g:512][j:8], k = kc*8+j
//   floats [81920, 82432)   : biasc = b_ih + b_hh
#define WS_WGF_H  32768
#define WS_BIAS_F 81920

typedef _Float16 f16x2 __attribute__((ext_vector_type(2)));
typedef _Float16 f16x8 __attribute__((ext_vector_type(8)));
typedef float    f32x4 __attribute__((ext_vector_type(4)));

__device__ __forceinline__ float sigm(float x) { return 1.0f / (1.0f + __expf(-x)); }

extern "C" __global__ void prep_kernel(const float* __restrict__ W_emb,
                                       const float* __restrict__ W_ih,
                                       const float* __restrict__ b_ih,
                                       const float* __restrict__ W_hh,
                                       const float* __restrict__ b_hh,
                                       float* __restrict__ ws) {
    int tid = blockIdx.x * blockDim.x + threadIdx.x;
    int nth = gridDim.x * blockDim.x;
    __half* WF    = (__half*)ws;
    __half* WG    = (__half*)ws + WS_WGF_H;
    float*  biasc = ws + WS_BIAS_F;
    for (int i = tid; i < 32768; i += nth) {
        int kg = i >> 10, m = (i >> 3) & 127, j = i & 7;
        WF[i] = __float2half(W_emb[m * 256 + kg * 8 + j]);
    }
    for (int i = tid; i < 131072; i += nth) {
        int kc = i >> 12, g = (i >> 3) & 511, j = i & 7;
        int k = kc * 8 + j;
        float w = (k < 128) ? W_ih[g * 128 + k] : W_hh[g * 128 + (k - 128)];
        WG[i] = __float2half(w);
    }
    for (int i = tid; i < 512; i += nth) biasc[i] = b_ih[i] + b_hh[i];
}

extern "C" __global__ __launch_bounds__(1024, 4)
void set2vec_main(const float* __restrict__ hidden,
                  const float* __restrict__ input,
                  const float* __restrict__ b_emb,
                  const unsigned char* __restrict__ mask_bytes,
                  const int* __restrict__ Tptr,
                  const float* __restrict__ ws,
                  float* __restrict__ out) {
    __shared__ __half2 mem2[NB][NN][MP2];    // 108800 B fp16 memory [bb][n][m-pair]
    __shared__ __half  xcath[NB][KD];        // fp16 [lstm_in | h] (gates A operand)
    __shared__ float   xcat2[NB][KD];        // fp32 [lstm_in | h]
    __shared__ float   cbuf[NB][MD];
    __shared__ float   emask[NB][NN];
    __shared__ float   bbuf[G4];
    __shared__ int     mask_is_u8;
    __shared__ float   gbuf[NB][G4];         // gates output
    __shared__ float   epart[NB][2][NN];     // [bb][m-half][n]
    __shared__ float   abuf[NB][NN];

    const int tid  = threadIdx.x;
    const int b0   = blockIdx.x * NB;
    const int lane = tid & 63, wv = tid >> 6;
    const int ln15 = lane & 15, lhi = lane >> 4;
    const __half* WF = (const __half*)ws;

    if (tid == 0) {
        int nz = 0;
        for (int i = 0; i < 64; ++i)
            if ((i & 3) && mask_bytes[i]) nz = 1;
        mask_is_u8 = nz;
    }

    // ---- fused embed via MFMA: mem = fp16(cat(hidden,input) @ W_emb^T + b_emb) ----
    {
        const float be0 = b_emb[0 * 16 + ln15], be1 = b_emb[1 * 16 + ln15];
        const float be2 = b_emb[2 * 16 + ln15], be3 = b_emb[3 * 16 + ln15];
        const float be4 = b_emb[4 * 16 + ln15], be5 = b_emb[5 * 16 + ln15];
        const float be6 = b_emb[6 * 16 + ln15], be7 = b_emb[7 * 16 + ln15];
        __half* memh = (__half*)mem2;
        for (int tile = wv; tile < 25; tile += 16) {   // 25 row-tiles of 16
            f32x4 acc0 = {be0, be0, be0, be0}, acc1 = {be1, be1, be1, be1};
            f32x4 acc2 = {be2, be2, be2, be2}, acc3 = {be3, be3, be3, be3};
            f32x4 acc4 = {be4, be4, be4, be4}, acc5 = {be5, be5, be5, be5};
            f32x4 acc6 = {be6, be6, be6, be6}, acc7 = {be7, be7, be7, be7};

            const int rA     = tile * 16 + ln15;
            const int rAok   = rA < NB * NN;
            const long gbase = ((long)(b0 * NN + rA)) << 7;

            #pragma unroll 1
            for (int mk = 0; mk < 8; ++mk) {
                f16x8 aF;
                if (rAok) {
                    int k0 = mk * 32 + lhi * 8;
                    const float* src = (k0 < 128) ? (hidden + gbase + k0)
                                                  : (input + gbase + (k0 - 128));
                    float4 v0 = *(const float4*)src;
                    float4 v1 = *(const float4*)(src + 4);
                    union { f16x8 v; f16x2 h[4]; } au;
                    au.h[0] = __builtin_bit_cast(f16x2, __builtin_amdgcn_cvt_pkrtz(v0.x, v0.y));
                    au.h[1] = __builtin_bit_cast(f16x2, __builtin_amdgcn_cvt_pkrtz(v0.z, v0.w));
                    au.h[2] = __builtin_bit_cast(f16x2, __builtin_amdgcn_cvt_pkrtz(v1.x, v1.y));
                    au.h[3] = __builtin_bit_cast(f16x2, __builtin_amdgcn_cvt_pkrtz(v1.z, v1.w));
                    aF = au.v;
                } else {
                    aF = (f16x8)(_Float16)0.0f;
                }
                const __half* wrow = WF + ((mk * 4 + lhi) * 128 + ln15) * 8;
#define EMB_CT(CT, ACC) { \
                union { uint4 u; f16x8 v; } bu; \
                bu.u = *(const uint4*)(wrow + (CT * 16) * 8); \
                ACC = __builtin_amdgcn_mfma_f32_16x16x32_f16(aF, bu.v, ACC, 0, 0, 0); }
                EMB_CT(0, acc0) EMB_CT(1, acc1) EMB_CT(2, acc2) EMB_CT(3, acc3)
                EMB_CT(4, acc4) EMB_CT(5, acc5) EMB_CT(6, acc6) EMB_CT(7, acc7)
#undef EMB_CT
            }
#define EMB_WR(CT, ACC) { \
            _Pragma("unroll") \
            for (int reg = 0; reg < 4; ++reg) { \
                int r = tile * 16 + lhi * 4 + reg; \
                if (r < NB * NN) { \
                    int bb = r / NN, n = r - (r / NN) * NN; \
                    memh[(bb * NN + n) * (2 * MP2) + CT * 16 + ln15] = __float2half(ACC[reg]); \
                } } }
            EMB_WR(0, acc0) EMB_WR(1, acc1) EMB_WR(2, acc2) EMB_WR(3, acc3)
            EMB_WR(4, acc4) EMB_WR(5, acc5) EMB_WR(6, acc6) EMB_WR(7, acc7)
#undef EMB_WR
        }
    }

    // ---- init LSTM state + mask + bias tables ----
    ((float*)xcat2)[tid] = 0.0f;                       // NB*KD = 1024
    ((__half*)xcath)[tid] = __float2half(0.0f);
    if (tid < NB * MD) ((float*)cbuf)[tid] = 0.0f;
    if (tid < G4) bbuf[tid] = ws[WS_BIAS_F + tid];
    if (tid < NB * NN) {
        int bb = tid / NN, n = tid - bb * NN;
        long mrow = (long)(b0 + bb) * NN + n;
        int valid = mask_is_u8 ? (mask_bytes[mrow] != 0)
                               : (((const int*)mask_bytes)[mrow] != 0);
        emask[bb][n] = valid ? 0.0f : BIG_NEG;
    }
    __syncthreads();

    const int T = Tptr[0];

    // ---- per-thread phase constants ----
    const uint4* WgB = (const uint4*)((const __half*)ws + WS_WGF_H);
    const int ct0 = wv * 2, ct1 = wv * 2 + 1;
    const __half* aBase = &xcath[ln15 & 3][lhi * 8];   // batch 0-3 on A rows 0-3 (dup'd)

    const int e_act = tid < 800;                       // energies: (bb, m-half, n)
    const int e_bb  = tid / 200;
    const int e_r   = tid - e_bb * 200;
    const int e_mh  = e_r / 100;
    const int e_n   = e_r - e_mh * 100;

    for (int step = 0; step < T; ++step) {
        // --- gates via MFMA: X[4,256] @ Wcat^T -> gbuf[4][512] ---
        {
            f32x4 ga = {0.f, 0.f, 0.f, 0.f}, gb = {0.f, 0.f, 0.f, 0.f};
            #pragma unroll 2
            for (int ks = 0; ks < 8; ++ks) {
                union { uint4 u; f16x8 v; } a, bA, bB;
                a.u = *(const uint4*)(aBase + ks * 32);
                int kc = ks * 4 + lhi;
                bA.u = WgB[kc * 512 + ct0 * 16 + ln15];
                ga = __builtin_amdgcn_mfma_f32_16x16x32_f16(a.v, bA.v, ga, 0, 0, 0);
                bB.u = WgB[kc * 512 + ct1 * 16 + ln15];
                gb = __builtin_amdgcn_mfma_f32_16x16x32_f16(a.v, bB.v, gb, 0, 0, 0);
            }
            if (lhi == 0) {   // D rows 0-3 = batches 0-3
                #pragma unroll
                for (int r = 0; r < 4; ++r) {
                    gbuf[r][ct0 * 16 + ln15] = ga[r];
                    gbuf[r][ct1 * 16 + ln15] = gb[r];
                }
            }
        }
        __syncthreads();
        // --- LSTM pointwise (i,f,g,o) ---
        if (tid < NB * MD) {
            int bb = tid >> 7, m = tid & 127;
            float gi = gbuf[bb][m]       + bbuf[m];
            float gf = gbuf[bb][128 + m] + bbuf[128 + m];
            float gg = gbuf[bb][256 + m] + bbuf[256 + m];
            float go = gbuf[bb][384 + m] + bbuf[384 + m];
            float c  = cbuf[bb][m];
            c = sigm(gf) * c + sigm(gi) * tanhf(gg);
            float qv = sigm(go) * tanhf(c);
            cbuf[bb][m] = c;
            xcat2[bb][128 + m] = qv;
            xcath[bb][128 + m] = __float2half(qv);
        }
        __syncthreads();
        // --- energies partial: M in halves ---
        if (e_act) {
            const uint4*  mr4 = (const uint4*)&mem2[e_bb][e_n][e_mh * 32];
            const float4* qv4 = (const float4*)&xcat2[e_bb][128 + e_mh * 64];
            float e = 0.0f;
            #pragma unroll
            for (int i = 0; i < 8; ++i) {
                uint4  mu = mr4[i];
                float4 qa = qv4[2 * i], qb = qv4[2 * i + 1];
                float2 m0 = __half22float2(*(__half2*)&mu.x);
                float2 m1 = __half22float2(*(__half2*)&mu.y);
                float2 m2 = __half22float2(*(__half2*)&mu.z);
                float2 m3 = __half22float2(*(__half2*)&mu.w);
                e = fmaf(qa.x, m0.x, e); e = fmaf(qa.y, m0.y, e);
                e = fmaf(qa.z, m1.x, e); e = fmaf(qa.w, m1.y, e);
                e = fmaf(qb.x, m2.x, e); e = fmaf(qb.y, m2.y, e);
                e = fmaf(qb.z, m3.x, e); e = fmaf(qb.w, m3.y, e);
            }
            ((float*)epart)[tid] = e;   // tid = bb*200 + mh*100 + n matches layout
        }
        __syncthreads();
        // --- softmax: 4 waves, one per batch ---
        if (tid < 256) {
            int bb = tid >> 6, l = tid & 63;
            const float* ep = &epart[bb][0][0];
            float e0 = ep[l] + ep[100 + l] + emask[bb][l];
            float e1 = -INFINITY;
            if (l < 36) {
                int n1 = l + 64;
                e1 = ep[n1] + ep[100 + n1] + emask[bb][n1];
            }
            float mx = fmaxf(e0, e1);
            for (int off = 32; off; off >>= 1) mx = fmaxf(mx, __shfl_xor(mx, off, 64));
            float p0 = __expf(e0 - mx);
            float p1 = (l < 36) ? __expf(e1 - mx) : 0.0f;
            float s = p0 + p1;
            for (int off = 32; off; off >>= 1) s += __shfl_xor(s, off, 64);
            float inv = 1.0f / s;
            abuf[bb][l] = p0 * inv;
            if (l < 36) abuf[bb][l + 64] = p1 * inv;
        }
        __syncthreads();
        // --- read: thread = (bb, m-pair) ---
        if (tid < 256) {
            int bb = tid >> 6, mp = tid & 63;
            const float*   ar  = abuf[bb];
            const __half2* mrp = &mem2[bb][0][mp];
            float r0 = 0, r1 = 0, r2 = 0, r3 = 0, s0 = 0, s1 = 0, s2 = 0, s3 = 0;
            #pragma unroll 5
            for (int n = 0; n < 100; n += 4) {
                float4  av = *(const float4*)(ar + n);
                __half2 h0 = mrp[n * MP2],       h1 = mrp[(n + 1) * MP2];
                __half2 h2 = mrp[(n + 2) * MP2], h3 = mrp[(n + 3) * MP2];
                float2 f0 = __half22float2(h0), f1 = __half22float2(h1);
                float2 f2 = __half22float2(h2), f3 = __half22float2(h3);
                r0 = fmaf(av.x, f0.x, r0); s0 = fmaf(av.x, f0.y, s0);
                r1 = fmaf(av.y, f1.x, r1); s1 = fmaf(av.y, f1.y, s1);
                r2 = fmaf(av.z, f2.x, r2); s2 = fmaf(av.z, f2.y, s2);
                r3 = fmaf(av.w, f3.x, r3); s3 = fmaf(av.w, f3.y, s3);
            }
            float rx = (r0 + r1) + (r2 + r3);
            float ry = (s0 + s1) + (s2 + s3);
            int m = mp * 2;
            xcat2[bb][m]     = rx;
            xcat2[bb][m + 1] = ry;
            xcath[bb][m]     = __float2half(rx);
            xcath[bb][m + 1] = __float2half(ry);
        }
        __syncthreads();
    }

    // ---- output: [q | read], 4 batches x 256 ----
    {
        int bb = tid >> 8, j = tid & 255;
        float v = (j < 128) ? xcat2[bb][128 + j] : xcat2[bb][j - 128];
        out[((long)(b0 + bb) << 8) + j] = v;
    }
}

extern "C" void kernel_launch(void* const* d_in, const int* in_sizes, int n_in,
                              void* d_out, int out_size, void* d_ws, size_t ws_size,
                              hipStream_t stream) {
    const float* hidden = (const float*)d_in[0];
    const float* input  = (const float*)d_in[1];
    const float* W_emb  = (const float*)d_in[2];
    const float* b_emb  = (const float*)d_in[3];
    const float* W_ih   = (const float*)d_in[4];
    const float* b_ih   = (const float*)d_in[5];
    const float* W_hh   = (const float*)d_in[6];
    const float* b_hh   = (const float*)d_in[7];
    const unsigned char* mask = (const unsigned char*)d_in[8];
    const int*  Tptr    = (const int*)d_in[9];
    float* ws   = (float*)d_ws;
    float* outp = (float*)d_out;

    hipLaunchKernelGGL(prep_kernel, dim3(128), dim3(256), 0, stream,
                       W_emb, W_ih, b_ih, W_hh, b_hh, ws);
    hipLaunchKernelGGL(set2vec_main, dim3(512), dim3(1024), 0, stream,
                       hidden, input, b_emb, mask, Tptr, ws, outp);
}

// Round 8
// 185.093 us; speedup vs baseline: 2.6200x; 1.0864x over previous
//
#include <hip/hip_runtime.h>
#include <hip/hip_fp16.h>
#include <math.h>

#define BIG_NEG  (-1.0e6f)
#define NN   100
#define MD   128
#define KD   256
#define G4   512
#define NB   4    // batch elements per block
#define MP2  68   // __half2 stride per mem row (272 B, 16B-aligned)
#define XPAD 288  // xcath row stride in halves: 576 B == 16 words mod 32 -> 2-way free

// ws layout:
//   halves [0, 32768)       : WembF embed B-frags [kg:32][m:128][j:8]
//   halves [32768, 163840)  : WGF gates B-frags [kc:32][g:512][j:8], k = kc*8+j
//   floats [81920, 82432)   : biasc = b_ih + b_hh
#define WS_WGF_H  32768
#define WS_BIAS_F 81920

typedef _Float16 f16x2 __attribute__((ext_vector_type(2)));
typedef _Float16 f16x8 __attribute__((ext_vector_type(8)));
typedef float    f32x4 __attribute__((ext_vector_type(4)));

__device__ __forceinline__ float sigm(float x) { return 1.0f / (1.0f + __expf(-x)); }

extern "C" __global__ void prep_kernel(const float* __restrict__ W_emb,
                                       const float* __restrict__ W_ih,
                                       const float* __restrict__ b_ih,
                                       const float* __restrict__ W_hh,
                                       const float* __restrict__ b_hh,
                                       float* __restrict__ ws) {
    int tid = blockIdx.x * blockDim.x + threadIdx.x;
    int nth = gridDim.x * blockDim.x;
    __half* WF    = (__half*)ws;
    __half* WG    = (__half*)ws + WS_WGF_H;
    float*  biasc = ws + WS_BIAS_F;
    for (int i = tid; i < 32768; i += nth) {
        int kg = i >> 10, m = (i >> 3) & 127, j = i & 7;
        WF[i] = __float2half(W_emb[m * 256 + kg * 8 + j]);
    }
    for (int i = tid; i < 131072; i += nth) {
        int kc = i >> 12, g = (i >> 3) & 511, j = i & 7;
        int k = kc * 8 + j;
        float w = (k < 128) ? W_ih[g * 128 + k] : W_hh[g * 128 + (k - 128)];
        WG[i] = __float2half(w);
    }
    for (int i = tid; i < 512; i += nth) biasc[i] = b_ih[i] + b_hh[i];
}

extern "C" __global__ __launch_bounds__(1024, 4)
void set2vec_main(const float* __restrict__ hidden,
                  const float* __restrict__ input,
                  const float* __restrict__ b_emb,
                  const unsigned char* __restrict__ mask_bytes,
                  const int* __restrict__ Tptr,
                  const float* __restrict__ ws,
                  float* __restrict__ out) {
    __shared__ __half2 mem2[NB][NN][MP2];    // 108800 B fp16 memory [bb][n][m-pair]
    __shared__ __half  xcath[NB][XPAD];      // fp16 [lstm_in | h] (gates A operand)
    __shared__ float   xcat2[NB][KD];        // fp32 [lstm_in | h]
    __shared__ float   cbuf[NB][MD];
    __shared__ float   emask[NB][NN];
    __shared__ float   bbuf[G4];
    __shared__ int     mask_is_u8;
    __shared__ float   gbuf[NB][G4];         // gates output
    __shared__ float   epart[NB][NN][2];     // [bb][n][m-half]
    __shared__ float   abuf[NB][NN];

    const int tid  = threadIdx.x;
    const int b0   = blockIdx.x * NB;
    const int lane = tid & 63, wv = tid >> 6;
    const int ln15 = lane & 15, lhi = lane >> 4;
    const __half* WF = (const __half*)ws;

    if (tid == 0) {
        int nz = 0;
        for (int i = 0; i < 64; ++i)
            if ((i & 3) && mask_bytes[i]) nz = 1;
        mask_is_u8 = nz;
    }

    // ---- fused embed via MFMA: mem = fp16(cat(hidden,input) @ W_emb^T + b_emb) ----
    {
        const float be0 = b_emb[0 * 16 + ln15], be1 = b_emb[1 * 16 + ln15];
        const float be2 = b_emb[2 * 16 + ln15], be3 = b_emb[3 * 16 + ln15];
        const float be4 = b_emb[4 * 16 + ln15], be5 = b_emb[5 * 16 + ln15];
        const float be6 = b_emb[6 * 16 + ln15], be7 = b_emb[7 * 16 + ln15];
        __half* memh = (__half*)mem2;
        for (int tile = wv; tile < 25; tile += 16) {   // 25 row-tiles of 16
            f32x4 acc0 = {be0, be0, be0, be0}, acc1 = {be1, be1, be1, be1};
            f32x4 acc2 = {be2, be2, be2, be2}, acc3 = {be3, be3, be3, be3};
            f32x4 acc4 = {be4, be4, be4, be4}, acc5 = {be5, be5, be5, be5};
            f32x4 acc6 = {be6, be6, be6, be6}, acc7 = {be7, be7, be7, be7};

            const int rA     = tile * 16 + ln15;
            const int rAok   = rA < NB * NN;
            const long gbase = ((long)(b0 * NN + rA)) << 7;

            #pragma unroll 1
            for (int mk = 0; mk < 8; ++mk) {
                f16x8 aF;
                if (rAok) {
                    int k0 = mk * 32 + lhi * 8;
                    const float* src = (k0 < 128) ? (hidden + gbase + k0)
                                                  : (input + gbase + (k0 - 128));
                    float4 v0 = *(const float4*)src;
                    float4 v1 = *(const float4*)(src + 4);
                    union { f16x8 v; f16x2 h[4]; } au;
                    au.h[0] = __builtin_bit_cast(f16x2, __builtin_amdgcn_cvt_pkrtz(v0.x, v0.y));
                    au.h[1] = __builtin_bit_cast(f16x2, __builtin_amdgcn_cvt_pkrtz(v0.z, v0.w));
                    au.h[2] = __builtin_bit_cast(f16x2, __builtin_amdgcn_cvt_pkrtz(v1.x, v1.y));
                    au.h[3] = __builtin_bit_cast(f16x2, __builtin_amdgcn_cvt_pkrtz(v1.z, v1.w));
                    aF = au.v;
                } else {
                    aF = (f16x8)(_Float16)0.0f;
                }
                const __half* wrow = WF + ((mk * 4 + lhi) * 128 + ln15) * 8;
#define EMB_CT(CT, ACC) { \
                union { uint4 u; f16x8 v; } bu; \
                bu.u = *(const uint4*)(wrow + (CT * 16) * 8); \
                ACC = __builtin_amdgcn_mfma_f32_16x16x32_f16(aF, bu.v, ACC, 0, 0, 0); }
                EMB_CT(0, acc0) EMB_CT(1, acc1) EMB_CT(2, acc2) EMB_CT(3, acc3)
                EMB_CT(4, acc4) EMB_CT(5, acc5) EMB_CT(6, acc6) EMB_CT(7, acc7)
#undef EMB_CT
            }
#define EMB_WR(CT, ACC) { \
            _Pragma("unroll") \
            for (int reg = 0; reg < 4; ++reg) { \
                int r = tile * 16 + lhi * 4 + reg; \
                if (r < NB * NN) { \
                    int bb = r / NN, n = r - (r / NN) * NN; \
                    memh[(bb * NN + n) * (2 * MP2) + CT * 16 + ln15] = __float2half(ACC[reg]); \
                } } }
            EMB_WR(0, acc0) EMB_WR(1, acc1) EMB_WR(2, acc2) EMB_WR(3, acc3)
            EMB_WR(4, acc4) EMB_WR(5, acc5) EMB_WR(6, acc6) EMB_WR(7, acc7)
#undef EMB_WR
        }
    }

    // ---- gate weights -> 16 named uint4 registers (step-invariant) ----
    const uint4* WgB = (const uint4*)((const __half*)ws + WS_WGF_H);
    const int ct0 = wv * 2, ct1 = wv * 2 + 1;
#define LDW(KS) \
    const uint4 wA##KS = WgB[((KS) * 4 + lhi) * 512 + ct0 * 16 + ln15]; \
    const uint4 wB##KS = WgB[((KS) * 4 + lhi) * 512 + ct1 * 16 + ln15];
    LDW(0) LDW(1) LDW(2) LDW(3) LDW(4) LDW(5) LDW(6) LDW(7)
#undef LDW

    // ---- init LSTM state + mask + bias tables ----
    for (int i = tid; i < NB * XPAD; i += 1024) ((__half*)xcath)[i] = __float2half(0.0f);
    ((float*)xcat2)[tid] = 0.0f;                       // NB*KD = 1024
    if (tid < NB * MD) ((float*)cbuf)[tid] = 0.0f;
    if (tid < G4) bbuf[tid] = ws[WS_BIAS_F + tid];
    if (tid < NB * NN) {
        int bb = tid / NN, n = tid - bb * NN;
        long mrow = (long)(b0 + bb) * NN + n;
        int valid = mask_is_u8 ? (mask_bytes[mrow] != 0)
                               : (((const int*)mask_bytes)[mrow] != 0);
        emask[bb][n] = valid ? 0.0f : BIG_NEG;
    }
    __syncthreads();

    const int T = Tptr[0];

    // ---- per-thread phase constants ----
    const __half* aBase = &xcath[ln15 & 3][lhi * 8];   // batch 0-3 on A rows 0-3 (dup'd)

    const int e_act = tid < 800;                       // energies: (bb, n, m-half)
    const int e_bb  = tid / 200;
    const int e_r   = tid - e_bb * 200;
    const int e_n   = e_r >> 1;
    const int e_mh  = e_r & 1;

    for (int step = 0; step < T; ++step) {
        // --- gates via MFMA: X[4,256] @ Wcat^T -> gbuf[4][512], weights in regs ---
        {
            f32x4 ga = {0.f, 0.f, 0.f, 0.f}, gb = {0.f, 0.f, 0.f, 0.f};
#define GS(KS) { \
            union { uint4 u; f16x8 v; } a, ba, bc; \
            a.u  = *(const uint4*)(aBase + (KS) * 32); \
            ba.u = wA##KS; bc.u = wB##KS; \
            ga = __builtin_amdgcn_mfma_f32_16x16x32_f16(a.v, ba.v, ga, 0, 0, 0); \
            gb = __builtin_amdgcn_mfma_f32_16x16x32_f16(a.v, bc.v, gb, 0, 0, 0); }
            GS(0) GS(1) GS(2) GS(3) GS(4) GS(5) GS(6) GS(7)
#undef GS
            if (lhi == 0) {   // D rows 0-3 = batches 0-3
                #pragma unroll
                for (int r = 0; r < 4; ++r) {
                    gbuf[r][ct0 * 16 + ln15] = ga[r];
                    gbuf[r][ct1 * 16 + ln15] = gb[r];
                }
            }
        }
        __syncthreads();
        // --- LSTM pointwise (i,f,g,o) ---
        if (tid < NB * MD) {
            int bb = tid >> 7, m = tid & 127;
            float gi = gbuf[bb][m]       + bbuf[m];
            float gf = gbuf[bb][128 + m] + bbuf[128 + m];
            float gg = gbuf[bb][256 + m] + bbuf[256 + m];
            float go = gbuf[bb][384 + m] + bbuf[384 + m];
            float c  = cbuf[bb][m];
            c = sigm(gf) * c + sigm(gi) * tanhf(gg);
            float qv = sigm(go) * tanhf(c);
            cbuf[bb][m] = c;
            xcat2[bb][128 + m] = qv;
            xcath[bb][128 + m] = __float2half(qv);
        }
        __syncthreads();
        // --- energies partial: thread = (bb, n, m-half); wave spans 32 n -> 4-way max ---
        if (e_act) {
            const uint4*  mr4 = (const uint4*)&mem2[e_bb][e_n][e_mh * 32];
            const float4* qv4 = (const float4*)&xcat2[e_bb][128 + e_mh * 64];
            float e = 0.0f;
            #pragma unroll
            for (int i = 0; i < 8; ++i) {
                uint4  mu = mr4[i];
                float4 qa = qv4[2 * i], qb = qv4[2 * i + 1];
                float2 m0 = __half22float2(*(__half2*)&mu.x);
                float2 m1 = __half22float2(*(__half2*)&mu.y);
                float2 m2 = __half22float2(*(__half2*)&mu.z);
                float2 m3 = __half22float2(*(__half2*)&mu.w);
                e = fmaf(qa.x, m0.x, e); e = fmaf(qa.y, m0.y, e);
                e = fmaf(qa.z, m1.x, e); e = fmaf(qa.w, m1.y, e);
                e = fmaf(qb.x, m2.x, e); e = fmaf(qb.y, m2.y, e);
                e = fmaf(qb.z, m3.x, e); e = fmaf(qb.w, m3.y, e);
            }
            epart[e_bb][e_n][e_mh] = e;
        }
        __syncthreads();
        // --- softmax: 4 waves, one per batch ---
        if (tid < 256) {
            int bb = tid >> 6, l = tid & 63;
            float e0 = epart[bb][l][0] + epart[bb][l][1] + emask[bb][l];
            float e1 = -INFINITY;
            if (l < 36) {
                int n1 = l + 64;
                e1 = epart[bb][n1][0] + epart[bb][n1][1] + emask[bb][n1];
            }
            float mx = fmaxf(e0, e1);
            for (int off = 32; off; off >>= 1) mx = fmaxf(mx, __shfl_xor(mx, off, 64));
            float p0 = __expf(e0 - mx);
            float p1 = (l < 36) ? __expf(e1 - mx) : 0.0f;
            float s = p0 + p1;
            for (int off = 32; off; off >>= 1) s += __shfl_xor(s, off, 64);
            float inv = 1.0f / s;
            abuf[bb][l] = p0 * inv;
            if (l < 36) abuf[bb][l + 64] = p1 * inv;
        }
        __syncthreads();
        // --- read: thread = (bb, m-pair) ---
        if (tid < 256) {
            int bb = tid >> 6, mp = tid & 63;
            const float*   ar  = abuf[bb];
            const __half2* mrp = &mem2[bb][0][mp];
            float r0 = 0, r1 = 0, r2 = 0, r3 = 0, s0 = 0, s1 = 0, s2 = 0, s3 = 0;
            #pragma unroll 5
            for (int n = 0; n < 100; n += 4) {
                float4  av = *(const float4*)(ar + n);
                __half2 h0 = mrp[n * MP2],       h1 = mrp[(n + 1) * MP2];
                __half2 h2 = mrp[(n + 2) * MP2], h3 = mrp[(n + 3) * MP2];
                float2 f0 = __half22float2(h0), f1 = __half22float2(h1);
                float2 f2 = __half22float2(h2), f3 = __half22float2(h3);
                r0 = fmaf(av.x, f0.x, r0); s0 = fmaf(av.x, f0.y, s0);
                r1 = fmaf(av.y, f1.x, r1); s1 = fmaf(av.y, f1.y, s1);
                r2 = fmaf(av.z, f2.x, r2); s2 = fmaf(av.z, f2.y, s2);
                r3 = fmaf(av.w, f3.x, r3); s3 = fmaf(av.w, f3.y, s3);
            }
            float rx = (r0 + r1) + (r2 + r3);
            float ry = (s0 + s1) + (s2 + s3);
            int m = mp * 2;
            xcat2[bb][m]     = rx;
            xcat2[bb][m + 1] = ry;
            xcath[bb][m]     = __float2half(rx);
            xcath[bb][m + 1] = __float2half(ry);
        }
        __syncthreads();
    }

    // ---- output: [q | read], 4 batches x 256 ----
    {
        int bb = tid >> 8, j = tid & 255;
        float v = (j < 128) ? xcat2[bb][128 + j] : xcat2[bb][j - 128];
        out[((long)(b0 + bb) << 8) + j] = v;
    }
}

extern "C" void kernel_launch(void* const* d_in, const int* in_sizes, int n_in,
                              void* d_out, int out_size, void* d_ws, size_t ws_size,
                              hipStream_t stream) {
    const float* hidden = (const float*)d_in[0];
    const float* input  = (const float*)d_in[1];
    const float* W_emb  = (const float*)d_in[2];
    const float* b_emb  = (const float*)d_in[3];
    const float* W_ih   = (const float*)d_in[4];
    const float* b_ih   = (const float*)d_in[5];
    const float* W_hh   = (const float*)d_in[6];
    const float* b_hh   = (const float*)d_in[7];
    const unsigned char* mask = (const unsigned char*)d_in[8];
    const int*  Tptr    = (const int*)d_in[9];
    float* ws   = (float*)d_ws;
    float* outp = (float*)d_out;

    hipLaunchKernelGGL(prep_kernel, dim3(128), dim3(256), 0, stream,
                       W_emb, W_ih, b_ih, W_hh, b_hh, ws);
    hipLaunchKernelGGL(set2vec_main, dim3(512), dim3(1024), 0, stream,
                       hidden, input, b_emb, mask, Tptr, ws, outp);
}

// Round 10
// 171.899 us; speedup vs baseline: 2.8211x; 1.0768x over previous
//
#include <hip/hip_runtime.h>
#include <hip/hip_fp16.h>
#include <math.h>

#define BIG_NEG  (-1.0e6f)
#define NN   100
#define MD   128
#define KD   256
#define G4   512
#define NB   4    // batch elements per block
#define MP2  68   // __half2 stride per mem row (272 B, 16B-aligned)
#define XPAD 288  // xcath row stride in halves: 576 B == 16 words mod 32 -> 2-way free

// ws layout:
//   halves [0, 32768)       : WembF embed B-frags [kg:32][m:128][j:8]
//   halves [32768, 163840)  : WGF gates B-frags [kc:32][g:512][j:8], k = kc*8+j
//   floats [81920, 82432)   : biasc = b_ih + b_hh
#define WS_WGF_H  32768
#define WS_BIAS_F 81920

typedef _Float16 f16x2 __attribute__((ext_vector_type(2)));
typedef _Float16 f16x8 __attribute__((ext_vector_type(8)));
typedef float    f32x4 __attribute__((ext_vector_type(4)));

#if __has_builtin(__builtin_amdgcn_rcpf)
#define RCPF(x) __builtin_amdgcn_rcpf(x)
#else
#define RCPF(x) (1.0f / (x))
#endif

#define PKRTZ(a, b) __builtin_bit_cast(unsigned, __builtin_amdgcn_cvt_pkrtz((a), (b)))

__device__ __forceinline__ float sigm(float x) {
    return RCPF(1.0f + __expf(-x));          // x<<0: exp=inf -> rcp=0, no NaN
}
__device__ __forceinline__ float tanh_f(float x) {
    float xc = fminf(fmaxf(x, -15.0f), 15.0f);
    float e  = __expf(2.0f * xc);
    return (e - 1.0f) * RCPF(e + 1.0f);
}

extern "C" __global__ void prep_kernel(const float* __restrict__ W_emb,
                                       const float* __restrict__ W_ih,
                                       const float* __restrict__ b_ih,
                                       const float* __restrict__ W_hh,
                                       const float* __restrict__ b_hh,
                                       float* __restrict__ ws) {
    int tid = blockIdx.x * blockDim.x + threadIdx.x;
    int nth = gridDim.x * blockDim.x;
    __half* WF    = (__half*)ws;
    __half* WG    = (__half*)ws + WS_WGF_H;
    float*  biasc = ws + WS_BIAS_F;
    for (int i = tid; i < 32768; i += nth) {
        int kg = i >> 10, m = (i >> 3) & 127, j = i & 7;
        WF[i] = __float2half(W_emb[m * 256 + kg * 8 + j]);
    }
    for (int i = tid; i < 131072; i += nth) {
        int kc = i >> 12, g = (i >> 3) & 511, j = i & 7;
        int k = kc * 8 + j;
        float w = (k < 128) ? W_ih[g * 128 + k] : W_hh[g * 128 + (k - 128)];
        WG[i] = __float2half(w);
    }
    for (int i = tid; i < 512; i += nth) biasc[i] = b_ih[i] + b_hh[i];
}

extern "C" __global__ __launch_bounds__(1024, 4)
void set2vec_main(const float* __restrict__ hidden,
                  const float* __restrict__ input,
                  const float* __restrict__ b_emb,
                  const unsigned char* __restrict__ mask_bytes,
                  const int* __restrict__ Tptr,
                  const float* __restrict__ ws,
                  float* __restrict__ out) {
    __shared__ __half2 mem2[NB][NN][MP2];    // 108800 B fp16 memory [bb][n][m-pair]
    __shared__ __half  xcath[NB][XPAD];      // fp16 [lstm_in | h] (MFMA A operand)
    __shared__ float   xcat2[NB][KD];        // fp32 [lstm_in | h]
    __shared__ float   cbuf[NB][MD];
    __shared__ float   emask[NB][NN];
    __shared__ float   bbuf[G4];
    __shared__ int     mask_is_u8;
    __shared__ float   gbuf[NB][G4];         // gates output
    __shared__ float   ebuf[NB][128];        // energies output
    __shared__ float   abuf[NB][NN];

    const int tid  = threadIdx.x;
    const int b0   = blockIdx.x * NB;
    const int lane = tid & 63, wv = tid >> 6;
    const int ln15 = lane & 15, lhi = lane >> 4;
    const __half* WF   = (const __half*)ws;
    const __half* memh = (const __half*)mem2;

    if (tid == 0) {
        int nz = 0;
        for (int i = 0; i < 64; ++i)
            if ((i & 3) && mask_bytes[i]) nz = 1;
        mask_is_u8 = nz;
    }

    // ---- fused embed via MFMA: mem = fp16(cat(hidden,input) @ W_emb^T + b_emb) ----
    {
        const float be0 = b_emb[0 * 16 + ln15], be1 = b_emb[1 * 16 + ln15];
        const float be2 = b_emb[2 * 16 + ln15], be3 = b_emb[3 * 16 + ln15];
        const float be4 = b_emb[4 * 16 + ln15], be5 = b_emb[5 * 16 + ln15];
        const float be6 = b_emb[6 * 16 + ln15], be7 = b_emb[7 * 16 + ln15];
        __half* memw = (__half*)mem2;
        for (int tile = wv; tile < 25; tile += 16) {   // 25 row-tiles of 16
            f32x4 acc0 = {be0, be0, be0, be0}, acc1 = {be1, be1, be1, be1};
            f32x4 acc2 = {be2, be2, be2, be2}, acc3 = {be3, be3, be3, be3};
            f32x4 acc4 = {be4, be4, be4, be4}, acc5 = {be5, be5, be5, be5};
            f32x4 acc6 = {be6, be6, be6, be6}, acc7 = {be7, be7, be7, be7};

            const int rA     = tile * 16 + ln15;
            const int rAok   = rA < NB * NN;
            const long gbase = ((long)(b0 * NN + rA)) << 7;

            #pragma unroll 1
            for (int mk = 0; mk < 8; ++mk) {
                f16x8 aF;
                if (rAok) {
                    int k0 = mk * 32 + lhi * 8;
                    const float* src = (k0 < 128) ? (hidden + gbase + k0)
                                                  : (input + gbase + (k0 - 128));
                    float4 v0 = *(const float4*)src;
                    float4 v1 = *(const float4*)(src + 4);
                    union { f16x8 v; unsigned u[4]; } au;
                    au.u[0] = PKRTZ(v0.x, v0.y);
                    au.u[1] = PKRTZ(v0.z, v0.w);
                    au.u[2] = PKRTZ(v1.x, v1.y);
                    au.u[3] = PKRTZ(v1.z, v1.w);
                    aF = au.v;
                } else {
                    aF = (f16x8)(_Float16)0.0f;
                }
                const __half* wrow = WF + ((mk * 4 + lhi) * 128 + ln15) * 8;
#define EMB_CT(CT, ACC) { \
                union { uint4 u; f16x8 v; } bu; \
                bu.u = *(const uint4*)(wrow + (CT * 16) * 8); \
                ACC = __builtin_amdgcn_mfma_f32_16x16x32_f16(aF, bu.v, ACC, 0, 0, 0); }
                EMB_CT(0, acc0) EMB_CT(1, acc1) EMB_CT(2, acc2) EMB_CT(3, acc3)
                EMB_CT(4, acc4) EMB_CT(5, acc5) EMB_CT(6, acc6) EMB_CT(7, acc7)
#undef EMB_CT
            }
#define EMB_WR(CT, ACC) { \
            _Pragma("unroll") \
            for (int reg = 0; reg < 4; ++reg) { \
                int r = tile * 16 + lhi * 4 + reg; \
                if (r < NB * NN) { \
                    int bb = r / NN, n = r - (r / NN) * NN; \
                    memw[(bb * NN + n) * (2 * MP2) + CT * 16 + ln15] = __float2half(ACC[reg]); \
                } } }
            EMB_WR(0, acc0) EMB_WR(1, acc1) EMB_WR(2, acc2) EMB_WR(3, acc3)
            EMB_WR(4, acc4) EMB_WR(5, acc5) EMB_WR(6, acc6) EMB_WR(7, acc7)
#undef EMB_WR
        }
    }

    // ---- gate weights -> 16 named uint4 registers (step-invariant) ----
    const uint4* WgB = (const uint4*)((const __half*)ws + WS_WGF_H);
    const int ct0 = wv * 2, ct1 = wv * 2 + 1;
#define LDW(KS) \
    const uint4 wA##KS = WgB[((KS) * 4 + lhi) * 512 + ct0 * 16 + ln15]; \
    const uint4 wB##KS = WgB[((KS) * 4 + lhi) * 512 + ct1 * 16 + ln15];
    LDW(0) LDW(1) LDW(2) LDW(3) LDW(4) LDW(5) LDW(6) LDW(7)
#undef LDW

    // ---- init LSTM state + mask + bias tables ----
    for (int i = tid; i < NB * XPAD; i += 1024) ((__half*)xcath)[i] = __float2half(0.0f);
    ((float*)xcat2)[tid] = 0.0f;                       // NB*KD = 1024
    if (tid < NB * MD) ((float*)cbuf)[tid] = 0.0f;
    if (tid < G4) bbuf[tid] = ws[WS_BIAS_F + tid];
    if (tid < NB * NN) {
        int bb = tid / NN, n = tid - bb * NN;
        long mrow = (long)(b0 + bb) * NN + n;
        int valid = mask_is_u8 ? (mask_bytes[mrow] != 0)
                               : (((const int*)mask_bytes)[mrow] != 0);
        emask[bb][n] = valid ? 0.0f : BIG_NEG;
    }
    __syncthreads();

    const int T = Tptr[0];

    // ---- per-thread phase constants ----
    const __half* aBase = &xcath[ln15 & 3][lhi * 8];   // batch 0-3 on A rows 0-3 (dup'd)

    // energies: wave wv<14 handles pairs (bb,ntile) p=2wv, 2wv+1 of 28
    const int ep0 = wv * 2, ep1 = wv * 2 + 1;
    const int e_bb0 = ep0 / 7, e_nt0 = ep0 - e_bb0 * 7;
    const int e_bb1 = ep1 / 7, e_nt1 = ep1 - e_bb1 * 7;
    const int e_n0  = e_nt0 * 16 + ln15, e_n1 = e_nt1 * 16 + ln15;
    const int e_n0c = (e_n0 < 100) ? e_n0 : 99;        // clamp OOB lanes (result discarded)
    const int e_n1c = (e_n1 < 100) ? e_n1 : 99;
    const __half* eB0 = memh + (e_bb0 * NN + e_n0c) * (2 * MP2) + lhi * 8;
    const __half* eB1 = memh + (e_bb1 * NN + e_n1c) * (2 * MP2) + lhi * 8;
    const __half* eA0 = &xcath[e_bb0][128 + lhi * 8];
    const __half* eA1 = &xcath[e_bb1][128 + lhi * 8];

    // read: 4 waves (bb = wv), lane = s*4 + nq; s = m-slice of 8, nq = n-quarter
    const int r_s = lane >> 2, r_nq = lane & 3;
    const __half* rBase = memh + (wv & 3) * NN * (2 * MP2) + r_s * 8;

    for (int step = 0; step < T; ++step) {
        // --- gates via MFMA: X[4,256] @ Wcat^T -> gbuf[4][512], weights in regs ---
        {
            f32x4 ga = {0.f, 0.f, 0.f, 0.f}, gb = {0.f, 0.f, 0.f, 0.f};
#define GS(KS) { \
            union { uint4 u; f16x8 v; } a, ba, bc; \
            a.u  = *(const uint4*)(aBase + (KS) * 32); \
            ba.u = wA##KS; bc.u = wB##KS; \
            ga = __builtin_amdgcn_mfma_f32_16x16x32_f16(a.v, ba.v, ga, 0, 0, 0); \
            gb = __builtin_amdgcn_mfma_f32_16x16x32_f16(a.v, bc.v, gb, 0, 0, 0); }
            GS(0) GS(1) GS(2) GS(3) GS(4) GS(5) GS(6) GS(7)
#undef GS
            if (lhi == 0) {   // D rows 0-3 = batches 0-3
                #pragma unroll
                for (int r = 0; r < 4; ++r) {
                    gbuf[r][ct0 * 16 + ln15] = ga[r];
                    gbuf[r][ct1 * 16 + ln15] = gb[r];
                }
            }
        }
        __syncthreads();
        // --- LSTM pointwise (i,f,g,o), fast transcendentals ---
        if (tid < NB * MD) {
            int bb = tid >> 7, m = tid & 127;
            float gi = gbuf[bb][m]       + bbuf[m];
            float gf = gbuf[bb][128 + m] + bbuf[128 + m];
            float gg = gbuf[bb][256 + m] + bbuf[256 + m];
            float go = gbuf[bb][384 + m] + bbuf[384 + m];
            float c  = cbuf[bb][m];
            c = sigm(gf) * c + sigm(gi) * tanh_f(gg);
            float qv = sigm(go) * tanh_f(c);
            cbuf[bb][m] = c;
            xcat2[bb][128 + m] = qv;
            xcath[bb][128 + m] = __float2half(qv);
        }
        __syncthreads();
        // --- energies via per-batch MFMA (A-rows broadcast = q_bb) ---
        if (wv < 14) {
            f32x4 e0 = {0.f, 0.f, 0.f, 0.f}, e1 = {0.f, 0.f, 0.f, 0.f};
#define ES(KS) { \
            union { uint4 u; f16x8 v; } a0, a1, bq0, bq1; \
            a0.u  = *(const uint4*)(eA0 + (KS) * 32); \
            bq0.u = *(const uint4*)(eB0 + (KS) * 32); \
            a1.u  = *(const uint4*)(eA1 + (KS) * 32); \
            bq1.u = *(const uint4*)(eB1 + (KS) * 32); \
            e0 = __builtin_amdgcn_mfma_f32_16x16x32_f16(a0.v, bq0.v, e0, 0, 0, 0); \
            e1 = __builtin_amdgcn_mfma_f32_16x16x32_f16(a1.v, bq1.v, e1, 0, 0, 0); }
            ES(0) ES(1) ES(2) ES(3)
#undef ES
            if (lhi == 0) {
                if (e_n0 < 100) ebuf[e_bb0][e_n0] = e0[0];
                if (e_n1 < 100) ebuf[e_bb1][e_n1] = e1[0];
            }
        }
        __syncthreads();
        // --- softmax: 4 waves, one per batch ---
        if (tid < 256) {
            int bb = tid >> 6, l = tid & 63;
            float e0 = ebuf[bb][l] + emask[bb][l];
            float e1 = -INFINITY;
            if (l < 36) e1 = ebuf[bb][l + 64] + emask[bb][l + 64];
            float mx = fmaxf(e0, e1);
            for (int off = 32; off; off >>= 1) mx = fmaxf(mx, __shfl_xor(mx, off, 64));
            float p0 = __expf(e0 - mx);
            float p1 = (l < 36) ? __expf(e1 - mx) : 0.0f;
            float s = p0 + p1;
            for (int off = 32; off; off >>= 1) s += __shfl_xor(s, off, 64);
            float inv = RCPF(s);
            abuf[bb][l] = p0 * inv;
            if (l < 36) abuf[bb][l + 64] = p1 * inv;
        }
        __syncthreads();
        // --- read: 4 waves, uint4 m-slices, in-wave nq combine ---
        if (tid < 256) {
            int bb = wv & 3;
            float a0 = 0.f, a1 = 0.f, a2 = 0.f, a3 = 0.f;
            float a4 = 0.f, a5 = 0.f, a6 = 0.f, a7 = 0.f;
            #pragma unroll 5
            for (int j = 0; j < 25; ++j) {
                int n = r_nq * 25 + j;
                float av = abuf[bb][n];
                uint4 u  = *(const uint4*)(rBase + n * (2 * MP2));
                float2 f0 = __half22float2(*(__half2*)&u.x);
                float2 f1 = __half22float2(*(__half2*)&u.y);
                float2 f2 = __half22float2(*(__half2*)&u.z);
                float2 f3 = __half22float2(*(__half2*)&u.w);
                a0 = fmaf(av, f0.x, a0); a1 = fmaf(av, f0.y, a1);
                a2 = fmaf(av, f1.x, a2); a3 = fmaf(av, f1.y, a3);
                a4 = fmaf(av, f2.x, a4); a5 = fmaf(av, f2.y, a5);
                a6 = fmaf(av, f3.x, a6); a7 = fmaf(av, f3.y, a7);
            }
#define RED(A) A += __shfl_xor(A, 1, 64); A += __shfl_xor(A, 2, 64);
            RED(a0) RED(a1) RED(a2) RED(a3) RED(a4) RED(a5) RED(a6) RED(a7)
#undef RED
            if (r_nq == 0) {
                int m = r_s * 8;
                float4 lo = {a0, a1, a2, a3}, hi = {a4, a5, a6, a7};
                *(float4*)&xcat2[bb][m]     = lo;
                *(float4*)&xcat2[bb][m + 4] = hi;
                uint4 hv;
                hv.x = PKRTZ(a0, a1);
                hv.y = PKRTZ(a2, a3);
                hv.z = PKRTZ(a4, a5);
                hv.w = PKRTZ(a6, a7);
                *(uint4*)&xcath[bb][m] = hv;
            }
        }
        __syncthreads();
    }

    // ---- output: [q | read], 4 batches x 256 ----
    {
        int bb = tid >> 8, j = tid & 255;
        float v = (j < 128) ? xcat2[bb][128 + j] : xcat2[bb][j - 128];
        out[((long)(b0 + bb) << 8) + j] = v;
    }
}

extern "C" void kernel_launch(void* const* d_in, const int* in_sizes, int n_in,
                              void* d_out, int out_size, void* d_ws, size_t ws_size,
                              hipStream_t stream) {
    const float* hidden = (const float*)d_in[0];
    const float* input  = (const float*)d_in[1];
    const float* W_emb  = (const float*)d_in[2];
    const float* b_emb  = (const float*)d_in[3];
    const float* W_ih   = (const float*)d_in[4];
    const float* b_ih   = (const float*)d_in[5];
    const float* W_hh   = (const float*)d_in[6];
    const float* b_hh   = (const float*)d_in[7];
    const unsigned char* mask = (const unsigned char*)d_in[8];
    const int*  Tptr    = (const int*)d_in[9];
    float* ws   = (float*)d_ws;
    float* outp = (float*)d_out;

    hipLaunchKernelGGL(prep_kernel, dim3(128), dim3(256), 0, stream,
                       W_emb, W_ih, b_ih, W_hh, b_hh, ws);
    hipLaunchKernelGGL(set2vec_main, dim3(512), dim3(1024), 0, stream,
                       hidden, input, b_emb, mask, Tptr, ws, outp);
}

// Round 11
// 165.545 us; speedup vs baseline: 2.9294x; 1.0384x over previous
//
#include <hip/hip_runtime.h>
#include <hip/hip_fp16.h>
#include <math.h>

#define BIG_NEG  (-1.0e6f)
#define NN   100
#define MD   128
#define KD   256
#define G4   512
#define NB   4    // batch elements per block
#define MP2  68   // __half2 stride per mem row (272 B, 16B-aligned)
#define XPAD 288  // xcath row stride in halves: 576 B == 16 words mod 32 -> 2-way free

// ws layout:
//   halves [0, 32768)       : WembF embed B-frags [kg:32][m:128][j:8]
//   halves [32768, 163840)  : WGF gates B-frags [kc:32][g:512][j:8], k = kc*8+j
//   floats [81920, 82432)   : biasc = b_ih + b_hh
#define WS_WGF_H  32768
#define WS_BIAS_F 81920

typedef _Float16 f16x2 __attribute__((ext_vector_type(2)));
typedef _Float16 f16x8 __attribute__((ext_vector_type(8)));
typedef float    f32x4 __attribute__((ext_vector_type(4)));

#if __has_builtin(__builtin_amdgcn_rcpf)
#define RCPF(x) __builtin_amdgcn_rcpf(x)
#else
#define RCPF(x) (1.0f / (x))
#endif

#define PKRTZ(a, b) __builtin_bit_cast(unsigned, __builtin_amdgcn_cvt_pkrtz((a), (b)))

__device__ __forceinline__ float sigm(float x) {
    return RCPF(1.0f + __expf(-x));          // x<<0: exp=inf -> rcp=0, no NaN
}
__device__ __forceinline__ float tanh_f(float x) {
    float xc = fminf(fmaxf(x, -15.0f), 15.0f);
    float e  = __expf(2.0f * xc);
    return (e - 1.0f) * RCPF(e + 1.0f);
}

extern "C" __global__ void prep_kernel(const float* __restrict__ W_emb,
                                       const float* __restrict__ W_ih,
                                       const float* __restrict__ b_ih,
                                       const float* __restrict__ W_hh,
                                       const float* __restrict__ b_hh,
                                       float* __restrict__ ws) {
    int tid = blockIdx.x * blockDim.x + threadIdx.x;
    int nth = gridDim.x * blockDim.x;
    __half* WF    = (__half*)ws;
    __half* WG    = (__half*)ws + WS_WGF_H;
    float*  biasc = ws + WS_BIAS_F;
    for (int i = tid; i < 32768; i += nth) {
        int kg = i >> 10, m = (i >> 3) & 127, j = i & 7;
        WF[i] = __float2half(W_emb[m * 256 + kg * 8 + j]);
    }
    for (int i = tid; i < 131072; i += nth) {
        int kc = i >> 12, g = (i >> 3) & 511, j = i & 7;
        int k = kc * 8 + j;
        float w = (k < 128) ? W_ih[g * 128 + k] : W_hh[g * 128 + (k - 128)];
        WG[i] = __float2half(w);
    }
    for (int i = tid; i < 512; i += nth) biasc[i] = b_ih[i] + b_hh[i];
}

extern "C" __global__ __launch_bounds__(1024, 4)
void set2vec_main(const float* __restrict__ hidden,
                  const float* __restrict__ input,
                  const float* __restrict__ b_emb,
                  const unsigned char* __restrict__ mask_bytes,
                  const int* __restrict__ Tptr,
                  const float* __restrict__ ws,
                  float* __restrict__ out) {
    __shared__ __half2 mem2[NB][NN][MP2];    // 108800 B fp16 memory [bb][n][m-pair]
    __shared__ __half  xcath[NB][XPAD];      // fp16 [lstm_in | h] (MFMA A operand)
    __shared__ float   xcat2[NB][KD];        // fp32 [lstm_in | h]
    __shared__ float   cbuf[NB][MD];
    __shared__ float   emask[NB][NN];
    __shared__ float   bbuf[G4];
    __shared__ int     mask_is_u8;
    __shared__ float   gbuf[NB][G4];         // gates output
    __shared__ float   ebuf[NB][128];        // energies output (mask folded in)
    __shared__ float   abuf[NB][NN];         // attn weights

    const int tid  = threadIdx.x;
    const int b0   = blockIdx.x * NB;
    const int lane = tid & 63, wv = tid >> 6;
    const int ln15 = lane & 15, lhi = lane >> 4;
    const __half* WF   = (const __half*)ws;
    const __half* memh = (const __half*)mem2;

    if (tid == 0) {
        int nz = 0;
        for (int i = 0; i < 64; ++i)
            if ((i & 3) && mask_bytes[i]) nz = 1;
        mask_is_u8 = nz;
    }

    // ---- fused embed via MFMA: mem = fp16(cat(hidden,input) @ W_emb^T + b_emb) ----
    {
        const float be0 = b_emb[0 * 16 + ln15], be1 = b_emb[1 * 16 + ln15];
        const float be2 = b_emb[2 * 16 + ln15], be3 = b_emb[3 * 16 + ln15];
        const float be4 = b_emb[4 * 16 + ln15], be5 = b_emb[5 * 16 + ln15];
        const float be6 = b_emb[6 * 16 + ln15], be7 = b_emb[7 * 16 + ln15];
        __half* memw = (__half*)mem2;
        for (int tile = wv; tile < 25; tile += 16) {   // 25 row-tiles of 16
            f32x4 acc0 = {be0, be0, be0, be0}, acc1 = {be1, be1, be1, be1};
            f32x4 acc2 = {be2, be2, be2, be2}, acc3 = {be3, be3, be3, be3};
            f32x4 acc4 = {be4, be4, be4, be4}, acc5 = {be5, be5, be5, be5};
            f32x4 acc6 = {be6, be6, be6, be6}, acc7 = {be7, be7, be7, be7};

            const int rA     = tile * 16 + ln15;
            const int rAok   = rA < NB * NN;
            const long gbase = ((long)(b0 * NN + rA)) << 7;

            #pragma unroll 1
            for (int mk = 0; mk < 8; ++mk) {
                f16x8 aF;
                if (rAok) {
                    int k0 = mk * 32 + lhi * 8;
                    const float* src = (k0 < 128) ? (hidden + gbase + k0)
                                                  : (input + gbase + (k0 - 128));
                    float4 v0 = *(const float4*)src;
                    float4 v1 = *(const float4*)(src + 4);
                    union { f16x8 v; unsigned u[4]; } au;
                    au.u[0] = PKRTZ(v0.x, v0.y);
                    au.u[1] = PKRTZ(v0.z, v0.w);
                    au.u[2] = PKRTZ(v1.x, v1.y);
                    au.u[3] = PKRTZ(v1.z, v1.w);
                    aF = au.v;
                } else {
                    aF = (f16x8)(_Float16)0.0f;
                }
                const __half* wrow = WF + ((mk * 4 + lhi) * 128 + ln15) * 8;
#define EMB_CT(CT, ACC) { \
                union { uint4 u; f16x8 v; } bu; \
                bu.u = *(const uint4*)(wrow + (CT * 16) * 8); \
                ACC = __builtin_amdgcn_mfma_f32_16x16x32_f16(aF, bu.v, ACC, 0, 0, 0); }
                EMB_CT(0, acc0) EMB_CT(1, acc1) EMB_CT(2, acc2) EMB_CT(3, acc3)
                EMB_CT(4, acc4) EMB_CT(5, acc5) EMB_CT(6, acc6) EMB_CT(7, acc7)
#undef EMB_CT
            }
#define EMB_WR(CT, ACC) { \
            _Pragma("unroll") \
            for (int reg = 0; reg < 4; ++reg) { \
                int r = tile * 16 + lhi * 4 + reg; \
                if (r < NB * NN) { \
                    int bb = r / NN, n = r - (r / NN) * NN; \
                    memw[(bb * NN + n) * (2 * MP2) + CT * 16 + ln15] = __float2half(ACC[reg]); \
                } } }
            EMB_WR(0, acc0) EMB_WR(1, acc1) EMB_WR(2, acc2) EMB_WR(3, acc3)
            EMB_WR(4, acc4) EMB_WR(5, acc5) EMB_WR(6, acc6) EMB_WR(7, acc7)
#undef EMB_WR
        }
    }

    // ---- gate weights -> 16 named uint4 registers (step-invariant) ----
    const uint4* WgB = (const uint4*)((const __half*)ws + WS_WGF_H);
    const int ct0 = wv * 2, ct1 = wv * 2 + 1;
#define LDW(KS) \
    const uint4 wA##KS = WgB[((KS) * 4 + lhi) * 512 + ct0 * 16 + ln15]; \
    const uint4 wB##KS = WgB[((KS) * 4 + lhi) * 512 + ct1 * 16 + ln15];
    LDW(0) LDW(1) LDW(2) LDW(3) LDW(4) LDW(5) LDW(6) LDW(7)
#undef LDW

    // ---- init LSTM state + mask + bias tables ----
    for (int i = tid; i < NB * XPAD; i += 1024) ((__half*)xcath)[i] = __float2half(0.0f);
    ((float*)xcat2)[tid] = 0.0f;                       // NB*KD = 1024
    if (tid < NB * MD) ((float*)cbuf)[tid] = 0.0f;
    if (tid < G4) bbuf[tid] = ws[WS_BIAS_F + tid];
    if (tid < NB * NN) {
        int bb = tid / NN, n = tid - bb * NN;
        long mrow = (long)(b0 + bb) * NN + n;
        int valid = mask_is_u8 ? (mask_bytes[mrow] != 0)
                               : (((const int*)mask_bytes)[mrow] != 0);
        emask[bb][n] = valid ? 0.0f : BIG_NEG;
    }
    __syncthreads();

    const int T = Tptr[0];

    // ---- per-thread phase constants ----
    const __half* aBase = &xcath[ln15 & 3][lhi * 8];   // batch 0-3 on A rows 0-3 (dup'd)

    // energies: wave wv<14 handles pairs (bb,ntile) p=2wv, 2wv+1 of 28
    const int ep0 = wv * 2, ep1 = wv * 2 + 1;
    const int e_bb0 = ep0 / 7, e_nt0 = ep0 - e_bb0 * 7;
    const int e_bb1 = ep1 / 7, e_nt1 = ep1 - e_bb1 * 7;
    const int e_n0  = e_nt0 * 16 + ln15, e_n1 = e_nt1 * 16 + ln15;
    const int e_n0c = (e_n0 < 100) ? e_n0 : 99;        // clamp OOB lanes (result discarded)
    const int e_n1c = (e_n1 < 100) ? e_n1 : 99;
    const __half* eB0 = memh + (e_bb0 * NN + e_n0c) * (2 * MP2) + lhi * 8;
    const __half* eB1 = memh + (e_bb1 * NN + e_n1c) * (2 * MP2) + lhi * 8;
    const __half* eA0 = &xcath[e_bb0][128 + lhi * 8];
    const __half* eA1 = &xcath[e_bb1][128 + lhi * 8];

    // fused softmax+read: 8 waves, wave = (bb = wv>>1, mh = wv&1)
    // lane = rg*8 + rs: rg = n-group (13,13,13,13,12,12,12,12), rs = m-slice of 8
    const int sr_bb = (wv >> 1) & 3, sr_mh = wv & 1;
    const int rg = lane >> 3, rs = lane & 7;
    const int r_start = (rg <= 4) ? rg * 13 : 64 + (rg - 5) * 12;
    const int r_cnt   = (rg < 4) ? 13 : 12;
    const __half* rB = memh + sr_bb * NN * (2 * MP2) + sr_mh * 64 + rs * 8;

    for (int step = 0; step < T; ++step) {
        // --- gates via MFMA: X[4,256] @ Wcat^T -> gbuf[4][512], weights in regs ---
        {
            f32x4 ga = {0.f, 0.f, 0.f, 0.f}, gb = {0.f, 0.f, 0.f, 0.f};
#define GS(KS) { \
            union { uint4 u; f16x8 v; } a, ba, bc; \
            a.u  = *(const uint4*)(aBase + (KS) * 32); \
            ba.u = wA##KS; bc.u = wB##KS; \
            ga = __builtin_amdgcn_mfma_f32_16x16x32_f16(a.v, ba.v, ga, 0, 0, 0); \
            gb = __builtin_amdgcn_mfma_f32_16x16x32_f16(a.v, bc.v, gb, 0, 0, 0); }
            GS(0) GS(1) GS(2) GS(3) GS(4) GS(5) GS(6) GS(7)
#undef GS
            if (lhi == 0) {   // D rows 0-3 = batches 0-3
                #pragma unroll
                for (int r = 0; r < 4; ++r) {
                    gbuf[r][ct0 * 16 + ln15] = ga[r];
                    gbuf[r][ct1 * 16 + ln15] = gb[r];
                }
            }
        }
        __syncthreads();
        // --- LSTM pointwise (i,f,g,o), fast transcendentals ---
        if (tid < NB * MD) {
            int bb = tid >> 7, m = tid & 127;
            float gi = gbuf[bb][m]       + bbuf[m];
            float gf = gbuf[bb][128 + m] + bbuf[128 + m];
            float gg = gbuf[bb][256 + m] + bbuf[256 + m];
            float go = gbuf[bb][384 + m] + bbuf[384 + m];
            float c  = cbuf[bb][m];
            c = sigm(gf) * c + sigm(gi) * tanh_f(gg);
            float qv = sigm(go) * tanh_f(c);
            cbuf[bb][m] = c;
            xcat2[bb][128 + m] = qv;
            xcath[bb][128 + m] = __float2half(qv);
        }
        __syncthreads();
        // --- energies via per-batch MFMA (A-rows broadcast = q_bb); emask folded in ---
        if (wv < 14) {
            f32x4 e0 = {0.f, 0.f, 0.f, 0.f}, e1 = {0.f, 0.f, 0.f, 0.f};
#define ES(KS) { \
            union { uint4 u; f16x8 v; } a0, a1, bq0, bq1; \
            a0.u  = *(const uint4*)(eA0 + (KS) * 32); \
            bq0.u = *(const uint4*)(eB0 + (KS) * 32); \
            a1.u  = *(const uint4*)(eA1 + (KS) * 32); \
            bq1.u = *(const uint4*)(eB1 + (KS) * 32); \
            e0 = __builtin_amdgcn_mfma_f32_16x16x32_f16(a0.v, bq0.v, e0, 0, 0, 0); \
            e1 = __builtin_amdgcn_mfma_f32_16x16x32_f16(a1.v, bq1.v, e1, 0, 0, 0); }
            ES(0) ES(1) ES(2) ES(3)
#undef ES
            if (lhi == 0) {
                if (e_n0 < 100) ebuf[e_bb0][e_n0] = e0[0] + emask[e_bb0][e_n0];
                if (e_n1 < 100) ebuf[e_bb1][e_n1] = e1[0] + emask[e_bb1][e_n1];
            }
        }
        __syncthreads();
        // --- fused softmax+read: 8 waves (2 per bb, redundant softmax) ---
        if (wv < 8) {
            // softmax in-wave (benign same-value race on abuf between the 2 waves per bb)
            {
                float e0 = ebuf[sr_bb][lane];
                float e1 = (lane < 36) ? ebuf[sr_bb][64 + lane] : -INFINITY;
                float mx = fmaxf(e0, e1);
                for (int off = 32; off; off >>= 1) mx = fmaxf(mx, __shfl_xor(mx, off, 64));
                float p0 = __expf(e0 - mx);
                float p1 = (lane < 36) ? __expf(e1 - mx) : 0.0f;
                float s = p0 + p1;
                for (int off = 32; off; off >>= 1) s += __shfl_xor(s, off, 64);
                float inv = RCPF(s);
                abuf[sr_bb][lane] = p0 * inv;
                if (lane < 36) abuf[sr_bb][64 + lane] = p1 * inv;
            }
            // read: each lane accumulates its n-group over its m-slice
            float a0 = 0.f, a1 = 0.f, a2 = 0.f, a3 = 0.f;
            float a4 = 0.f, a5 = 0.f, a6 = 0.f, a7 = 0.f;
            #pragma unroll
            for (int j = 0; j < 13; ++j) {
                if (j < r_cnt) {
                    int n = r_start + j;
                    float av = abuf[sr_bb][n];
                    uint4 u  = *(const uint4*)(rB + n * (2 * MP2));
                    float2 f0 = __half22float2(*(__half2*)&u.x);
                    float2 f1 = __half22float2(*(__half2*)&u.y);
                    float2 f2 = __half22float2(*(__half2*)&u.z);
                    float2 f3 = __half22float2(*(__half2*)&u.w);
                    a0 = fmaf(av, f0.x, a0); a1 = fmaf(av, f0.y, a1);
                    a2 = fmaf(av, f1.x, a2); a3 = fmaf(av, f1.y, a3);
                    a4 = fmaf(av, f2.x, a4); a5 = fmaf(av, f2.y, a5);
                    a6 = fmaf(av, f3.x, a6); a7 = fmaf(av, f3.y, a7);
                }
            }
#define RED(A) A += __shfl_xor(A, 8, 64); A += __shfl_xor(A, 16, 64); A += __shfl_xor(A, 32, 64);
            RED(a0) RED(a1) RED(a2) RED(a3) RED(a4) RED(a5) RED(a6) RED(a7)
#undef RED
            if (lane < 8) {     // rg == 0 lanes hold full sums; rs == lane
                int m = sr_mh * 64 + lane * 8;
                float4 lo = {a0, a1, a2, a3}, hi = {a4, a5, a6, a7};
                *(float4*)&xcat2[sr_bb][m]     = lo;
                *(float4*)&xcat2[sr_bb][m + 4] = hi;
                uint4 hv;
                hv.x = PKRTZ(a0, a1);
                hv.y = PKRTZ(a2, a3);
                hv.z = PKRTZ(a4, a5);
                hv.w = PKRTZ(a6, a7);
                *(uint4*)&xcath[sr_bb][m] = hv;
            }
        }
        __syncthreads();
    }

    // ---- output: [q | read], 4 batches x 256 ----
    {
        int bb = tid >> 8, j = tid & 255;
        float v = (j < 128) ? xcat2[bb][128 + j] : xcat2[bb][j - 128];
        out[((long)(b0 + bb) << 8) + j] = v;
    }
}

extern "C" void kernel_launch(void* const* d_in, const int* in_sizes, int n_in,
                              void* d_out, int out_size, void* d_ws, size_t ws_size,
                              hipStream_t stream) {
    const float* hidden = (const float*)d_in[0];
    const float* input  = (const float*)d_in[1];
    const float* W_emb  = (const float*)d_in[2];
    const float* b_emb  = (const float*)d_in[3];
    const float* W_ih   = (const float*)d_in[4];
    const float* b_ih   = (const float*)d_in[5];
    const float* W_hh   = (const float*)d_in[6];
    const float* b_hh   = (const float*)d_in[7];
    const unsigned char* mask = (const unsigned char*)d_in[8];
    const int*  Tptr    = (const int*)d_in[9];
    float* ws   = (float*)d_ws;
    float* outp = (float*)d_out;

    hipLaunchKernelGGL(prep_kernel, dim3(128), dim3(256), 0, stream,
                       W_emb, W_ih, b_ih, W_hh, b_hh, ws);
    hipLaunchKernelGGL(set2vec_main, dim3(512), dim3(1024), 0, stream,
                       hidden, input, b_emb, mask, Tptr, ws, outp);
}

// Round 13
// 164.430 us; speedup vs baseline: 2.9493x; 1.0068x over previous
//
#include <hip/hip_runtime.h>
#include <hip/hip_fp16.h>
#include <math.h>

#define BIG_NEG  (-1.0e6f)
#define NN   100
#define MD   128
#define KD   256
#define G4   512
#define NB   4    // batch elements per block
#define MP2  68   // __half2 stride per mem row (272 B, 16B-aligned)
#define XPAD 288  // xcath row stride in halves: 576 B == 16 words mod 32 -> 2-way free

// ws layout:
//   halves [0, 32768)       : WembF embed B-frags [kg:32][m:128][j:8]
//   halves [32768, 163840)  : WGF gates B-frags [kc:32][g:512][j:8], k = kc*8+j
//   floats [81920, 82432)   : biasc = b_ih + b_hh
#define WS_WGF_H  32768
#define WS_BIAS_F 81920

typedef _Float16 f16x2 __attribute__((ext_vector_type(2)));
typedef _Float16 f16x8 __attribute__((ext_vector_type(8)));
typedef float    f32x4 __attribute__((ext_vector_type(4)));

#if __has_builtin(__builtin_amdgcn_rcpf)
#define RCPF(x) __builtin_amdgcn_rcpf(x)
#else
#define RCPF(x) (1.0f / (x))
#endif

#define PKRTZ(a, b) __builtin_bit_cast(unsigned, __builtin_amdgcn_cvt_pkrtz((a), (b)))

__device__ __forceinline__ float sigm(float x) {
    return RCPF(1.0f + __expf(-x));          // x<<0: exp=inf -> rcp=0, no NaN
}
__device__ __forceinline__ float tanh_f(float x) {
    float xc = fminf(fmaxf(x, -15.0f), 15.0f);
    float e  = __expf(2.0f * xc);
    return (e - 1.0f) * RCPF(e + 1.0f);
}

extern "C" __global__ void prep_kernel(const float* __restrict__ W_emb,
                                       const float* __restrict__ W_ih,
                                       const float* __restrict__ b_ih,
                                       const float* __restrict__ W_hh,
                                       const float* __restrict__ b_hh,
                                       float* __restrict__ ws) {
    int tid = blockIdx.x * blockDim.x + threadIdx.x;
    int nth = gridDim.x * blockDim.x;
    __half* WF    = (__half*)ws;
    __half* WG    = (__half*)ws + WS_WGF_H;
    float*  biasc = ws + WS_BIAS_F;
    for (int i = tid; i < 32768; i += nth) {
        int kg = i >> 10, m = (i >> 3) & 127, j = i & 7;
        WF[i] = __float2half(W_emb[m * 256 + kg * 8 + j]);
    }
    for (int i = tid; i < 131072; i += nth) {
        int kc = i >> 12, g = (i >> 3) & 511, j = i & 7;
        int k = kc * 8 + j;
        float w = (k < 128) ? W_ih[g * 128 + k] : W_hh[g * 128 + (k - 128)];
        WG[i] = __float2half(w);
    }
    for (int i = tid; i < 512; i += nth) biasc[i] = b_ih[i] + b_hh[i];
}

extern "C" __global__ __launch_bounds__(1024, 4)
__attribute__((amdgpu_waves_per_eu(4, 4)))
void set2vec_main(const float* __restrict__ hidden,
                  const float* __restrict__ input,
                  const float* __restrict__ b_emb,
                  const unsigned char* __restrict__ mask_bytes,
                  const int* __restrict__ Tptr,
                  const float* __restrict__ ws,
                  float* __restrict__ out) {
    __shared__ __half2 mem2[NB][NN][MP2];    // 108800 B fp16 memory [bb][n][m-pair]
    __shared__ __half  xcath[NB][XPAD];      // fp16 [lstm_in | h] (MFMA A operand)
    __shared__ float   xcat2[NB][KD];        // fp32 [lstm_in | h]
    __shared__ float   cbuf[NB][MD];
    __shared__ float   emask[NB][NN];
    __shared__ float   bbuf[G4];
    __shared__ int     mask_is_u8;
    __shared__ float   gbuf[NB][G4];         // gates output
    __shared__ float   ebuf[NB][128];        // energies output (mask folded in)
    __shared__ float   abuf[NB][NN];         // attn weights

    const int tid  = threadIdx.x;
    const int b0   = blockIdx.x * NB;
    const int lane = tid & 63, wv = tid >> 6;
    const int ln15 = lane & 15, lhi = lane >> 4;
    const __half* WF   = (const __half*)ws;
    const __half* memh = (const __half*)mem2;

    if (tid == 0) {
        int nz = 0;
        for (int i = 0; i < 64; ++i)
            if ((i & 3) && mask_bytes[i]) nz = 1;
        mask_is_u8 = nz;
    }

    // ---- fused embed via MFMA: mem = fp16(cat(hidden,input) @ W_emb^T + b_emb) ----
    {
        const float be0 = b_emb[0 * 16 + ln15], be1 = b_emb[1 * 16 + ln15];
        const float be2 = b_emb[2 * 16 + ln15], be3 = b_emb[3 * 16 + ln15];
        const float be4 = b_emb[4 * 16 + ln15], be5 = b_emb[5 * 16 + ln15];
        const float be6 = b_emb[6 * 16 + ln15], be7 = b_emb[7 * 16 + ln15];
        __half* memw = (__half*)mem2;
        for (int tile = wv; tile < 25; tile += 16) {   // 25 row-tiles of 16
            f32x4 acc0 = {be0, be0, be0, be0}, acc1 = {be1, be1, be1, be1};
            f32x4 acc2 = {be2, be2, be2, be2}, acc3 = {be3, be3, be3, be3};
            f32x4 acc4 = {be4, be4, be4, be4}, acc5 = {be5, be5, be5, be5};
            f32x4 acc6 = {be6, be6, be6, be6}, acc7 = {be7, be7, be7, be7};

            const int rA     = tile * 16 + ln15;
            const int rAok   = rA < NB * NN;
            const long gbase = ((long)(b0 * NN + rA)) << 7;

            #pragma unroll 1
            for (int mk = 0; mk < 8; ++mk) {
                f16x8 aF;
                if (rAok) {
                    int k0 = mk * 32 + lhi * 8;
                    const float* src = (k0 < 128) ? (hidden + gbase + k0)
                                                  : (input + gbase + (k0 - 128));
                    float4 v0 = *(const float4*)src;
                    float4 v1 = *(const float4*)(src + 4);
                    union { f16x8 v; unsigned u[4]; } au;
                    au.u[0] = PKRTZ(v0.x, v0.y);
                    au.u[1] = PKRTZ(v0.z, v0.w);
                    au.u[2] = PKRTZ(v1.x, v1.y);
                    au.u[3] = PKRTZ(v1.z, v1.w);
                    aF = au.v;
                } else {
                    aF = (f16x8)(_Float16)0.0f;
                }
                const __half* wrow = WF + ((mk * 4 + lhi) * 128 + ln15) * 8;
#define EMB_CT(CT, ACC) { \
                union { uint4 u; f16x8 v; } bu; \
                bu.u = *(const uint4*)(wrow + (CT * 16) * 8); \
                ACC = __builtin_amdgcn_mfma_f32_16x16x32_f16(aF, bu.v, ACC, 0, 0, 0); }
                EMB_CT(0, acc0) EMB_CT(1, acc1) EMB_CT(2, acc2) EMB_CT(3, acc3)
                EMB_CT(4, acc4) EMB_CT(5, acc5) EMB_CT(6, acc6) EMB_CT(7, acc7)
#undef EMB_CT
            }
#define EMB_WR(CT, ACC) { \
            _Pragma("unroll") \
            for (int reg = 0; reg < 4; ++reg) { \
                int r = tile * 16 + lhi * 4 + reg; \
                if (r < NB * NN) { \
                    int bb = r / NN, n = r - (r / NN) * NN; \
                    memw[(bb * NN + n) * (2 * MP2) + CT * 16 + ln15] = __float2half(ACC[reg]); \
                } } }
            EMB_WR(0, acc0) EMB_WR(1, acc1) EMB_WR(2, acc2) EMB_WR(3, acc3)
            EMB_WR(4, acc4) EMB_WR(5, acc5) EMB_WR(6, acc6) EMB_WR(7, acc7)
#undef EMB_WR
        }
    }

    // ---- gate weights -> 16 named uint4 registers (step-invariant, forced resident) ----
    const uint4* WgB = (const uint4*)((const __half*)ws + WS_WGF_H);
    const int ct0 = wv * 2, ct1 = wv * 2 + 1;
#define LDW(KS) \
    uint4 wA##KS = WgB[((KS) * 4 + lhi) * 512 + ct0 * 16 + ln15]; \
    uint4 wB##KS = WgB[((KS) * 4 + lhi) * 512 + ct1 * 16 + ln15];
    LDW(0) LDW(1) LDW(2) LDW(3) LDW(4) LDW(5) LDW(6) LDW(7)
#undef LDW
    // opacity per 32-bit component: compiler cannot rematerialize from memory each step
#define OPQ(X) asm volatile("" : "+v"(X.x), "+v"(X.y), "+v"(X.z), "+v"(X.w));
    OPQ(wA0) OPQ(wA1) OPQ(wA2) OPQ(wA3) OPQ(wA4) OPQ(wA5) OPQ(wA6) OPQ(wA7)
    OPQ(wB0) OPQ(wB1) OPQ(wB2) OPQ(wB3) OPQ(wB4) OPQ(wB5) OPQ(wB6) OPQ(wB7)
#undef OPQ

    // ---- init LSTM state + mask + bias tables ----
    for (int i = tid; i < NB * XPAD; i += 1024) ((__half*)xcath)[i] = __float2half(0.0f);
    ((float*)xcat2)[tid] = 0.0f;                       // NB*KD = 1024
    if (tid < NB * MD) ((float*)cbuf)[tid] = 0.0f;
    if (tid < G4) bbuf[tid] = ws[WS_BIAS_F + tid];
    if (tid < NB * NN) {
        int bb = tid / NN, n = tid - bb * NN;
        long mrow = (long)(b0 + bb) * NN + n;
        int valid = mask_is_u8 ? (mask_bytes[mrow] != 0)
                               : (((const int*)mask_bytes)[mrow] != 0);
        emask[bb][n] = valid ? 0.0f : BIG_NEG;
    }
    __syncthreads();

    const int T = Tptr[0];

    // ---- per-thread phase constants ----
    const __half* aBase = &xcath[ln15 & 3][lhi * 8];   // batch 0-3 on A rows 0-3 (dup'd)

    // energies: wave wv<14 handles pairs (bb,ntile) p=2wv, 2wv+1 of 28
    const int ep0 = wv * 2, ep1 = wv * 2 + 1;
    const int e_bb0 = ep0 / 7, e_nt0 = ep0 - e_bb0 * 7;
    const int e_bb1 = ep1 / 7, e_nt1 = ep1 - e_bb1 * 7;
    const int e_n0  = e_nt0 * 16 + ln15, e_n1 = e_nt1 * 16 + ln15;
    const int e_n0c = (e_n0 < 100) ? e_n0 : 99;        // clamp OOB lanes (result discarded)
    const int e_n1c = (e_n1 < 100) ? e_n1 : 99;
    const __half* eB0 = memh + (e_bb0 * NN + e_n0c) * (2 * MP2) + lhi * 8;
    const __half* eB1 = memh + (e_bb1 * NN + e_n1c) * (2 * MP2) + lhi * 8;
    const __half* eA0 = &xcath[e_bb0][128 + lhi * 8];
    const __half* eA1 = &xcath[e_bb1][128 + lhi * 8];

    // fused softmax+read: 8 waves, wave = (bb = wv>>1, mh = wv&1)
    // lane = rg*8 + rs: rg = n-group (13,13,13,13,12,12,12,12), rs = m-slice of 8
    const int sr_bb = (wv >> 1) & 3, sr_mh = wv & 1;
    const int rg = lane >> 3, rs = lane & 7;
    const int r_start = (rg <= 4) ? rg * 13 : 64 + (rg - 5) * 12;
    const int r_cnt   = (rg < 4) ? 13 : 12;
    const __half* rB = memh + sr_bb * NN * (2 * MP2) + sr_mh * 64 + rs * 8;

    for (int step = 0; step < T; ++step) {
        // --- gates via MFMA: X[4,256] @ Wcat^T -> gbuf[4][512], weights in regs ---
        {
            f32x4 ga = {0.f, 0.f, 0.f, 0.f}, gb = {0.f, 0.f, 0.f, 0.f};
#define GS(KS) { \
            union { uint4 u; f16x8 v; } a, ba, bc; \
            a.u  = *(const uint4*)(aBase + (KS) * 32); \
            ba.u = wA##KS; bc.u = wB##KS; \
            ga = __builtin_amdgcn_mfma_f32_16x16x32_f16(a.v, ba.v, ga, 0, 0, 0); \
            gb = __builtin_amdgcn_mfma_f32_16x16x32_f16(a.v, bc.v, gb, 0, 0, 0); }
            GS(0) GS(1) GS(2) GS(3) GS(4) GS(5) GS(6) GS(7)
#undef GS
            if (lhi == 0) {   // D rows 0-3 = batches 0-3
                #pragma unroll
                for (int r = 0; r < 4; ++r) {
                    gbuf[r][ct0 * 16 + ln15] = ga[r];
                    gbuf[r][ct1 * 16 + ln15] = gb[r];
                }
            }
        }
        __syncthreads();
        // --- LSTM pointwise (i,f,g,o), fast transcendentals ---
        if (tid < NB * MD) {
            int bb = tid >> 7, m = tid & 127;
            float gi = gbuf[bb][m]       + bbuf[m];
            float gf = gbuf[bb][128 + m] + bbuf[128 + m];
            float gg = gbuf[bb][256 + m] + bbuf[256 + m];
            float go = gbuf[bb][384 + m] + bbuf[384 + m];
            float c  = cbuf[bb][m];
            c = sigm(gf) * c + sigm(gi) * tanh_f(gg);
            float qv = sigm(go) * tanh_f(c);
            cbuf[bb][m] = c;
            xcat2[bb][128 + m] = qv;
            xcath[bb][128 + m] = __float2half(qv);
        }
        __syncthreads();
        // --- energies via per-batch MFMA (A-rows broadcast = q_bb); emask folded in ---
        if (wv < 14) {
            f32x4 e0 = {0.f, 0.f, 0.f, 0.f}, e1 = {0.f, 0.f, 0.f, 0.f};
#define ES(KS) { \
            union { uint4 u; f16x8 v; } a0, a1, bq0, bq1; \
            a0.u  = *(const uint4*)(eA0 + (KS) * 32); \
            bq0.u = *(const uint4*)(eB0 + (KS) * 32); \
            a1.u  = *(const uint4*)(eA1 + (KS) * 32); \
            bq1.u = *(const uint4*)(eB1 + (KS) * 32); \
            e0 = __builtin_amdgcn_mfma_f32_16x16x32_f16(a0.v, bq0.v, e0, 0, 0, 0); \
            e1 = __builtin_amdgcn_mfma_f32_16x16x32_f16(a1.v, bq1.v, e1, 0, 0, 0); }
            ES(0) ES(1) ES(2) ES(3)
#undef ES
            if (lhi == 0) {
                if (e_n0 < 100) ebuf[e_bb0][e_n0] = e0[0] + emask[e_bb0][e_n0];
                if (e_n1 < 100) ebuf[e_bb1][e_n1] = e1[0] + emask[e_bb1][e_n1];
            }
        }
        __syncthreads();
        // --- fused softmax+read: 8 waves (2 per bb, redundant softmax) ---
        if (wv < 8) {
            // softmax in-wave (benign same-value race on abuf between the 2 waves per bb)
            {
                float e0 = ebuf[sr_bb][lane];
                float e1 = (lane < 36) ? ebuf[sr_bb][64 + lane] : -INFINITY;
                float mx = fmaxf(e0, e1);
                for (int off = 32; off; off >>= 1) mx = fmaxf(mx, __shfl_xor(mx, off, 64));
                float p0 = __expf(e0 - mx);
                float p1 = (lane < 36) ? __expf(e1 - mx) : 0.0f;
                float s = p0 + p1;
                for (int off = 32; off; off >>= 1) s += __shfl_xor(s, off, 64);
                float inv = RCPF(s);
                abuf[sr_bb][lane] = p0 * inv;
                if (lane < 36) abuf[sr_bb][64 + lane] = p1 * inv;
            }
            // read: each lane accumulates its n-group over its m-slice
            float a0 = 0.f, a1 = 0.f, a2 = 0.f, a3 = 0.f;
            float a4 = 0.f, a5 = 0.f, a6 = 0.f, a7 = 0.f;
            #pragma unroll
            for (int j = 0; j < 13; ++j) {
                if (j < r_cnt) {
                    int n = r_start + j;
                    float av = abuf[sr_bb][n];
                    uint4 u  = *(const uint4*)(rB + n * (2 * MP2));
                    float2 f0 = __half22float2(*(__half2*)&u.x);
                    float2 f1 = __half22float2(*(__half2*)&u.y);
                    float2 f2 = __half22float2(*(__half2*)&u.z);
                    float2 f3 = __half22float2(*(__half2*)&u.w);
                    a0 = fmaf(av, f0.x, a0); a1 = fmaf(av, f0.y, a1);
                    a2 = fmaf(av, f1.x, a2); a3 = fmaf(av, f1.y, a3);
                    a4 = fmaf(av, f2.x, a4); a5 = fmaf(av, f2.y, a5);
                    a6 = fmaf(av, f3.x, a6); a7 = fmaf(av, f3.y, a7);
                }
            }
#define RED(A) A += __shfl_xor(A, 8, 64); A += __shfl_xor(A, 16, 64); A += __shfl_xor(A, 32, 64);
            RED(a0) RED(a1) RED(a2) RED(a3) RED(a4) RED(a5) RED(a6) RED(a7)
#undef RED
            if (lane < 8) {     // rg == 0 lanes hold full sums; rs == lane
                int m = sr_mh * 64 + lane * 8;
                float4 lo = {a0, a1, a2, a3}, hi = {a4, a5, a6, a7};
                *(float4*)&xcat2[sr_bb][m]     = lo;
                *(float4*)&xcat2[sr_bb][m + 4] = hi;
                uint4 hv;
                hv.x = PKRTZ(a0, a1);
                hv.y = PKRTZ(a2, a3);
                hv.z = PKRTZ(a4, a5);
                hv.w = PKRTZ(a6, a7);
                *(uint4*)&xcath[sr_bb][m] = hv;
            }
        }
        __syncthreads();
    }

    // ---- output: [q | read], 4 batches x 256 ----
    {
        int bb = tid >> 8, j = tid & 255;
        float v = (j < 128) ? xcat2[bb][128 + j] : xcat2[bb][j - 128];
        out[((long)(b0 + bb) << 8) + j] = v;
    }
}

extern "C" void kernel_launch(void* const* d_in, const int* in_sizes, int n_in,
                              void* d_out, int out_size, void* d_ws, size_t ws_size,
                              hipStream_t stream) {
    const float* hidden = (const float*)d_in[0];
    const float* input  = (const float*)d_in[1];
    const float* W_emb  = (const float*)d_in[2];
    const float* b_emb  = (const float*)d_in[3];
    const float* W_ih   = (const float*)d_in[4];
    const float* b_ih   = (const float*)d_in[5];
    const float* W_hh   = (const float*)d_in[6];
    const float* b_hh   = (const float*)d_in[7];
    const unsigned char* mask = (const unsigned char*)d_in[8];
    const int*  Tptr    = (const int*)d_in[9];
    float* ws   = (float*)d_ws;
    float* outp = (float*)d_out;

    hipLaunchKernelGGL(prep_kernel, dim3(128), dim3(256), 0, stream,
                       W_emb, W_ih, b_ih, W_hh, b_hh, ws);
    hipLaunchKernelGGL(set2vec_main, dim3(512), dim3(1024), 0, stream,
                       hidden, input, b_emb, mask, Tptr, ws, outp);
}